// Round 16
// baseline (205.582 us; speedup 1.0000x reference)
//
#include <hip/hip_runtime.h>
#include <math.h>

// Retention (B=4, S=4096, D=256): chunkwise, split-bf16 MFMA, packed k8-slab
// operands.
// R1-R15: see history. R15 = 194.9us (64-row retile of scores/lmat/out).
// R16: proj retiled BM=32 (grid 512x1x3 = 6 blocks/CU vs 3; proj was
//   grid-limited). Wave tile 32x64 (acc[2][4]), SLABC=264 A-dbuf (8.4KB),
//   quad-unit X split staging, single-unit epilogues. Others unchanged.
#define BB 4
#define SS 4096
#define DD 256
#define LL 256
#define NCH 16
#define GAMMA 0.9865f
#define LOG2G (-0.019609034f)   // log2(0.9865)
#define INV1MG 74.07407407f     // 1/(1-gamma)
#define SLAB 1032               // padded LDS slab stride (u16), 128-row panels
#define SLABB 520               // padded LDS slab stride (u16), 64-row panels
#define SLABC 264               // padded LDS slab stride (u16), 32-row panels

typedef __attribute__((ext_vector_type(8))) short short8;
typedef __attribute__((ext_vector_type(4))) short short4v;
typedef __attribute__((ext_vector_type(4))) float f32x4;
typedef unsigned short u16;
typedef unsigned int u32;

__device__ __forceinline__ u16 f2bf(float f) {
  union { float f; unsigned u; } v; v.f = f;
  unsigned r = v.u + 0x7FFFu + ((v.u >> 16) & 1u);
  return (u16)(r >> 16);
}
__device__ __forceinline__ float bf2f(u16 h) {
  union { unsigned u; float f; } v; v.u = ((unsigned)h) << 16; return v.f;
}

__device__ __forceinline__ void gll16(const u16* g, u16* l) {
  __builtin_amdgcn_global_load_lds(
      (const __attribute__((address_space(1))) u32*)g,
      (__attribute__((address_space(3))) u32*)l, 16, 0, 0);
}
// stage one BK=32 k-step of 64 rows from a 128-row panel (row offset folded
// into g by caller): 4 slabs x 64 rows, SLABB stride
__device__ __forceinline__ void stageB64(const u16* g, u16* l, int lane) {
#pragma unroll
  for (int i = 0; i < 4; ++i)
    gll16(g + i * 1024 + lane * 8, l + i * SLABB);
}

// 32-row A from LDS (SLABC slabs), B regs[4]; 32x64 per wave (proj R16)
__device__ __forceinline__ void mfma_step_regB32(
    const u16* Ah, const u16* Al, const short8 bh[4], const short8 bl[4],
    int fm, int fq, f32x4 acc[2][4])
{
  const int ka = fq * SLABC;
  short8 ah[2], al[2];
#pragma unroll
  for (int i = 0; i < 2; ++i) {
    ah[i] = *(const short8*)&Ah[ka + (i * 16 + fm) * 8];
    al[i] = *(const short8*)&Al[ka + (i * 16 + fm) * 8];
  }
#pragma unroll
  for (int j = 0; j < 4; ++j)
#pragma unroll
    for (int i = 0; i < 2; ++i) {
      acc[i][j] = __builtin_amdgcn_mfma_f32_16x16x32_bf16(al[i], bh[j], acc[i][j], 0, 0, 0);
      acc[i][j] = __builtin_amdgcn_mfma_f32_16x16x32_bf16(ah[i], bl[j], acc[i][j], 0, 0, 0);
      acc[i][j] = __builtin_amdgcn_mfma_f32_16x16x32_bf16(ah[i], bh[j], acc[i][j], 0, 0, 0);
    }
}

// 64-row-A tile (SLABB stride), wave does 32x32: A rows wm0+{0,16}, B regs[2]
__device__ __forceinline__ void mfma_64_ab(
    const u16* Ah, const u16* Al, const short8 bh[2], const short8 bl[2],
    int wm0, int fm, int fq, f32x4 acc[2][2])
{
  const int ka = fq * SLABB;
  short8 ah[2], al[2];
#pragma unroll
  for (int i = 0; i < 2; ++i) {
    ah[i] = *(const short8*)&Ah[ka + (wm0 + i * 16 + fm) * 8];
    al[i] = *(const short8*)&Al[ka + (wm0 + i * 16 + fm) * 8];
  }
#pragma unroll
  for (int j = 0; j < 2; ++j)
#pragma unroll
    for (int i = 0; i < 2; ++i) {
      acc[i][j] = __builtin_amdgcn_mfma_f32_16x16x32_bf16(al[i], bh[j], acc[i][j], 0, 0, 0);
      acc[i][j] = __builtin_amdgcn_mfma_f32_16x16x32_bf16(ah[i], bl[j], acc[i][j], 0, 0, 0);
      acc[i][j] = __builtin_amdgcn_mfma_f32_16x16x32_bf16(ah[i], bh[j], acc[i][j], 0, 0, 0);
    }
}

// 64-row tile, A and B both from SLABB-stride LDS, wave 32x32 (out-intra)
__device__ __forceinline__ void mfma_64_bb(
    const u16* Ah, const u16* Al, const u16* Bh, const u16* Bl,
    int wm0, int wn0, int fm, int fq, f32x4 acc[2][2])
{
  const int ka = fq * SLABB;
  short8 ah[2], al[2];
#pragma unroll
  for (int i = 0; i < 2; ++i) {
    ah[i] = *(const short8*)&Ah[ka + (wm0 + i * 16 + fm) * 8];
    al[i] = *(const short8*)&Al[ka + (wm0 + i * 16 + fm) * 8];
  }
#pragma unroll
  for (int j = 0; j < 2; ++j) {
    short8 bh = *(const short8*)&Bh[ka + (wn0 + j * 16 + fm) * 8];
    short8 bl = *(const short8*)&Bl[ka + (wn0 + j * 16 + fm) * 8];
#pragma unroll
    for (int i = 0; i < 2; ++i) {
      acc[i][j] = __builtin_amdgcn_mfma_f32_16x16x32_bf16(al[i], bh, acc[i][j], 0, 0, 0);
      acc[i][j] = __builtin_amdgcn_mfma_f32_16x16x32_bf16(ah[i], bl, acc[i][j], 0, 0, 0);
      acc[i][j] = __builtin_amdgcn_mfma_f32_16x16x32_bf16(ah[i], bh, acc[i][j], 0, 0, 0);
    }
  }
}

// load a wave's 64-row-panel B-fragments (2 col-groups, hi+lo) from global.
__device__ __forceinline__ void loadB2(short8 bh[2], short8 bl[2],
    const u16* BhP, const u16* BlP, int ks, int wn0, int fm, int fq)
{
  const int base = ks * 4096 + fq * 1024;
#pragma unroll
  for (int j = 0; j < 2; ++j) {
    int o = base + (wn0 + j * 16 + fm) * 8;
    bh[j] = *(const short8*)&BhP[o];
    bl[j] = *(const short8*)&BlP[o];
  }
}

// ---------------------------------------------------------------------------
// 0) pack W^T slabs (hi/lo) + zero rsP/lVec accumulators. grid (3, 16).
__global__ __launch_bounds__(256) void init_pack_kernel(
    const float* __restrict__ Wq, const float* __restrict__ Wk, const float* __restrict__ Wv,
    u16* __restrict__ Wth, u16* __restrict__ Wtl,
    float* __restrict__ rsP, float* __restrict__ lVec)
{
  const int which = blockIdx.x;
  const int it = blockIdx.y;
  const int t = threadIdx.x;
  if (which == 0) {
    *(float4*)&rsP[(size_t)(it * 256 + t) * 4] = (float4){0.f, 0.f, 0.f, 0.f};
  } else if (which == 1) {
    *(float4*)&lVec[(size_t)(it * 256 + t) * 4] = (float4){0.f, 0.f, 0.f, 0.f};
  }
  const float* W = which == 0 ? Wq : (which == 1 ? Wk : Wv);
  for (int pn = 0; pn < 2; ++pn) {
    int pos = it * 256 + t;
    int k8 = pos >> 7, r = pos & 127;
    u16 hs[8], ls[8];
#pragma unroll
    for (int u = 0; u < 8; ++u) {
      float x = W[(size_t)(k8 * 8 + u) * DD + pn * 128 + r];
      u16 h = f2bf(x); hs[u] = h; ls[u] = f2bf(x - bf2f(h));
    }
    size_t o = ((size_t)((which * 2 + pn) * 32 + k8)) * 1024 + (size_t)r * 8;
    *(short8*)&Wth[o] = *(short8*)hs;
    *(short8*)&Wtl[o] = *(short8*)ls;
  }
}

// ---------------------------------------------------------------------------
// 1) projections (R16): BM=32 x BN=256, grid (512,1,3) -> 6 blocks/CU.
//    A: fp32 X (32x32/step) quad-unit reg-prefetched, split into SLABC dbuf.
//    B: W^T frags in regs per wave (4 col-groups over its 64-col strip).
//    4 quarter-width single-unit epilogues.
__global__ __launch_bounds__(256, 4) void proj_kernel(
    const float* __restrict__ xq, const float* __restrict__ xk, const float* __restrict__ xv,
    const u16* __restrict__ Wth, const u16* __restrict__ Wtl,
    const float* __restrict__ bq, const float* __restrict__ bk_, const float* __restrict__ bv,
    u16* __restrict__ Qh, u16* __restrict__ Ql,
    u16* __restrict__ Kh, u16* __restrict__ Kl,
    u16* __restrict__ KTh, u16* __restrict__ KTl,
    u16* __restrict__ VTh, u16* __restrict__ VTl,
    float* __restrict__ lVec)
{
  const int which = blockIdx.z;
  const float* bias = which == 0 ? bq : (which == 1 ? bk_ : bv);
  const int m0 = blockIdx.x * 32;
  __shared__ u16 SM[16 * SLABC];          // A dbuf (2 x (4hi+4lo) SLABC slabs)
  __shared__ float rsc[32];
  __shared__ float wlut[32];
  __shared__ float kacc[64];
  float* fb = (float*)SM;                 // 32x65 fp32 bounce (epilogue only)
  const int tid = threadIdx.x, lane = tid & 63, wave = tid >> 6;
  const int wn0g = wave * 64;             // wave's global col strip
  const int fm = lane & 15, fq = lane >> 4;
  if (which == 1) {
    if (tid < 32) {
      int sb = (m0 & (SS - 1)) + tid;
      rsc[tid] = rsqrtf((1.0f - exp2f((float)(sb + 1) * LOG2G)) * INV1MG);
      wlut[tid] = exp2f((float)(255 - ((m0 & (LL - 1)) + tid)) * LOG2G);
    }
    if (tid < 64) kacc[tid] = 0.f;
  }
  const float* XP = (which == 0 ? xq : (which == 1 ? xk : xv)) + (size_t)m0 * DD;
  const int pnw = wn0g >> 7, wl = wn0g & 127;
  const u16* WhP = Wth + (size_t)((which * 2 + pnw) * 32) * 1024;
  const u16* WlP = Wtl + (size_t)((which * 2 + pnw) * 32) * 1024;
  const int arow = tid >> 3, aq4 = tid & 7;  // 32 rows x 8 quad-cols
  f32x4 acc[2][4];
#pragma unroll
  for (int i = 0; i < 2; ++i)
#pragma unroll
    for (int j = 0; j < 4; ++j) acc[i][j] = (f32x4){0.f, 0.f, 0.f, 0.f};
  float xs[4];
  short8 bh[4], bl[4];
  // prologue: W(0) into regs, X(0) into buffer 0
  {
    const int base = fq * 1024;
#pragma unroll
    for (int j = 0; j < 4; ++j) {
      int o = base + (wl + j * 16 + fm) * 8;
      bh[j] = *(const short8*)&WhP[o];
      bl[j] = *(const short8*)&WlP[o];
    }
  }
  {
    float4 x4 = *(const float4*)(XP + (size_t)arow * DD + aq4 * 4);
    xs[0] = x4.x; xs[1] = x4.y; xs[2] = x4.z; xs[3] = x4.w;
    u16 hs[4], ls[4];
#pragma unroll
    for (int u = 0; u < 4; ++u) {
      u16 h = f2bf(xs[u]); hs[u] = h; ls[u] = f2bf(xs[u] - bf2f(h));
    }
    int k8 = aq4 >> 1, sub = aq4 & 1;
    *(short4v*)&SM[k8 * SLABC + arow * 8 + sub * 4] = *(short4v*)hs;
    *(short4v*)&SM[4 * SLABC + k8 * SLABC + arow * 8 + sub * 4] = *(short4v*)ls;
  }
  int cur = 0;
  for (int ks = 0; ks < 8; ++ks) {
    __syncthreads();                       // buf[cur] ready
    u16* Ac = SM + cur * 8 * SLABC;
    u16* An = SM + (cur ^ 1) * 8 * SLABC;
    if (ks < 7) {
      float4 x4 = *(const float4*)(XP + (size_t)arow * DD + (ks + 1) * 32 + aq4 * 4);
      xs[0] = x4.x; xs[1] = x4.y; xs[2] = x4.z; xs[3] = x4.w;
    }
    mfma_step_regB32(Ac, Ac + 4 * SLABC, bh, bl, fm, fq, acc);
    if (ks < 7) {
      const int base = (ks + 1) * 4096 + fq * 1024;
#pragma unroll
      for (int j = 0; j < 4; ++j) {        // prefetch next W frags
        int o = base + (wl + j * 16 + fm) * 8;
        bh[j] = *(const short8*)&WhP[o];
        bl[j] = *(const short8*)&WlP[o];
      }
      u16 hs[4], ls[4];
#pragma unroll
      for (int u = 0; u < 4; ++u) {
        u16 h = f2bf(xs[u]); hs[u] = h; ls[u] = f2bf(xs[u] - bf2f(h));
      }
      int k8 = aq4 >> 1, sub = aq4 & 1;
      *(short4v*)&An[k8 * SLABC + arow * 8 + sub * 4] = *(short4v*)hs;
      *(short4v*)&An[4 * SLABC + k8 * SLABC + arow * 8 + sub * 4] = *(short4v*)ls;
    }
    cur ^= 1;
  }
  const int b = m0 >> 12, sbb = m0 & (SS - 1);
  for (int p = 0; p < 4; ++p) {            // quarter-width column passes
    __syncthreads();
    if (wn0g == p * 64) {                  // owning wave bounces acc -> fb
#pragma unroll
      for (int i = 0; i < 2; ++i)
#pragma unroll
        for (int j = 0; j < 4; ++j)
#pragma unroll
          for (int r = 0; r < 4; ++r)
            fb[(i * 16 + fq * 4 + r) * 65 + j * 16 + fm] = acc[i][j][r];
    }
    __syncthreads();
    if (which == 0) {
      int k8l = tid >> 5, row = tid & 31;  // 8 k8 x 32 rows, 1 unit/thread
      int gc0 = p * 64 + k8l * 8;
      u16 hs[8], ls[8];
#pragma unroll
      for (int u = 0; u < 8; ++u) {
        float v = (fb[row * 65 + k8l * 8 + u] + bias[gc0 + u]) * (1.f / 16.f);
        u16 h = f2bf(v); hs[u] = h; ls[u] = f2bf(v - bf2f(h));
      }
      size_t o = (size_t)(m0 >> 7) * 32768 + (size_t)(p * 8 + k8l) * 1024 +
                 (size_t)((m0 & 127) + row) * 8;
      *(short8*)&Qh[o] = *(short8*)hs;
      *(short8*)&Ql[o] = *(short8*)ls;
    } else if (which == 1) {
      {                                    // K (row-major panel)
        int k8l = tid >> 5, row = tid & 31;
        int gc0 = p * 64 + k8l * 8;
        u16 hs[8], ls[8];
#pragma unroll
        for (int u = 0; u < 8; ++u) {
          float v = (fb[row * 65 + k8l * 8 + u] + bias[gc0 + u]) * rsc[row];
          u16 h = f2bf(v); hs[u] = h; ls[u] = f2bf(v - bf2f(h));
        }
        size_t o = (size_t)(m0 >> 7) * 32768 + (size_t)(p * 8 + k8l) * 1024 +
                   (size_t)((m0 & 127) + row) * 8;
        *(short8*)&Kh[o] = *(short8*)hs;
        *(short8*)&Kl[o] = *(short8*)ls;
      }
      {                                    // KT (col-major packed) + lVec
        int dl = tid & 63, s8l = tid >> 6;
        int gcolg = p * 64 + dl;
        float bs = bias[gcolg];
        float kpart = 0.f;
        u16 hs[8], ls[8];
#pragma unroll
        for (int u = 0; u < 8; ++u) {
          int row = s8l * 8 + u;
          float v = (fb[row * 65 + dl] + bs) * rsc[row];
          kpart = fmaf(v, wlut[row], kpart);
          u16 h = f2bf(v); hs[u] = h; ls[u] = f2bf(v - bf2f(h));
        }
        int sb0 = sbb + s8l * 8;
        size_t o = ((size_t)(b * 2 + (gcolg >> 7)) * 512 + (sb0 >> 3)) * 1024 + (size_t)(gcolg & 127) * 8;
        *(short8*)&KTh[o] = *(short8*)hs;
        *(short8*)&KTl[o] = *(short8*)ls;
        atomicAdd(&kacc[dl], kpart);
      }
      __syncthreads();
      if (tid < 64) {
        int c = sbb >> 8;
        atomicAdd(&lVec[(size_t)(b * NCH + c) * DD + p * 64 + tid], kacc[tid]);
        kacc[tid] = 0.f;
      }
    } else {  // V: split-bf16, KT-packed layout
      int dl = tid & 63, s8l = tid >> 6;
      int gcolg = p * 64 + dl;
      float bs = bias[gcolg];
      u16 hs[8], ls[8];
#pragma unroll
      for (int u = 0; u < 8; ++u) {
        float v = fb[(s8l * 8 + u) * 65 + dl] + bs;
        u16 h = f2bf(v); hs[u] = h; ls[u] = f2bf(v - bf2f(h));
      }
      int sb0 = sbb + s8l * 8;
      size_t o = ((size_t)(b * 2 + (gcolg >> 7)) * 512 + (sb0 >> 3)) * 1024 + (size_t)(gcolg & 127) * 8;
      *(short8*)&VTh[o] = *(short8*)hs;
      *(short8*)&VTl[o] = *(short8*)ls;
    }
  }
}

// ---------------------------------------------------------------------------
// 3) Sg = mask*(Q~.K~)*g^(il-jl); fused rowsum + Q.cVec dot -> rsP atomics.
//    R14: 64x64 tiles, causal triangle grid (64 x 10). A = Q 64-row half
//    panel via stageB64 dbuf; B = K frags global->regs. Wave tile 32x32.
__global__ __launch_bounds__(256, 4) void scores_kernel(
    const u16* __restrict__ Qh, const u16* __restrict__ Ql,
    const u16* __restrict__ Kh, const u16* __restrict__ Kl,
    const float* __restrict__ lVec, u16* __restrict__ Sgh, u16* __restrict__ Sgl,
    float* __restrict__ rsP)
{
  const int chunk = blockIdx.x, b = chunk >> 4, c = chunk & 15;
  const int y = blockIdx.y;
  const int mi = (y >= 6) ? 3 : (y >= 3) ? 2 : (y >= 1) ? 1 : 0;
  const int ji = y - mi * (mi + 1) / 2;
  const int m0 = mi * 64, jn0 = ji * 64;
  __shared__ u16 SA[2 * 8 * SLABB];
  __shared__ float cv[256], lut[256], rowAcc[64], qd4[4][64];
  float* fb = (float*)SA;  // 64x65 fp32 = 16640B = |SA| (epilogue only)
  const int tid = threadIdx.x, lane = tid & 63, wave = tid >> 6;
  const int wm0 = (wave >> 1) * 32, wn0 = (wave & 1) * 32;
  const int fm = lane & 15, fq = lane >> 4;
  if (jn0 == 0) {  // inline prefix scan: cv = sum_{cp<c} gL^(c-1-cp) lVec[cp]
    const float gL = exp2f((float)LL * LOG2G);
    float s = 0.f;
    for (int cp = 0; cp < c; ++cp)
      s = fmaf(gL, s, lVec[(size_t)(b * NCH + cp) * DD + tid]);
    cv[tid] = s;
  }
  lut[tid] = exp2f((float)tid * LOG2G);
  if (tid < 64) rowAcc[tid] = 0.f;
  const int growA = b * SS + c * LL + m0;
  const int growB = b * SS + c * LL + jn0;
  const u16* QhP = Qh + (size_t)(growA >> 7) * 32768 + (size_t)(growA & 127) * 8;
  const u16* QlP = Ql + (size_t)(growA >> 7) * 32768 + (size_t)(growA & 127) * 8;
  const u16* KhP = Kh + (size_t)(growB >> 7) * 32768 + (size_t)(growB & 127) * 8;
  const u16* KlP = Kl + (size_t)(growB >> 7) * 32768 + (size_t)(growB & 127) * 8;
  f32x4 acc[2][2];
#pragma unroll
  for (int i = 0; i < 2; ++i)
#pragma unroll
    for (int j = 0; j < 2; ++j) acc[i][j] = (f32x4){0.f, 0.f, 0.f, 0.f};
  float qdreg = 0.f;
  const int qrow = tid & 63, qk8b = tid >> 6;  // 64 rows x 4 k8
  short8 bh[2], bl[2];
  if (wave == 0) stageB64(QhP, SA, lane);
  if (wave == 1) stageB64(QlP, SA + 4 * SLABB, lane);
  loadB2(bh, bl, KhP, KlP, 0, wn0, fm, fq);
  int cur = 0;
  for (int ks = 0; ks < 8; ++ks) {
    __syncthreads();
    u16* Ac = cur ? SA + 8 * SLABB : SA;
    u16* An = cur ? SA : SA + 8 * SLABB;
    if (ks < 7) {
      if (wave == 0) stageB64(QhP + (ks + 1) * 4096, An, lane);
      if (wave == 1) stageB64(QlP + (ks + 1) * 4096, An + 4 * SLABB, lane);
    }
    mfma_64_ab(Ac, Ac + 4 * SLABB, bh, bl, wm0, fm, fq, acc);
    if (ks < 7) loadB2(bh, bl, KhP, KlP, ks + 1, wn0, fm, fq);
    if (jn0 == 0) {
      short8 hv = *(const short8*)&Ac[qk8b * SLABB + qrow * 8];
      short8 lv = *(const short8*)&Ac[4 * SLABB + qk8b * SLABB + qrow * 8];
#pragma unroll
      for (int u = 0; u < 8; ++u)
        qdreg = fmaf(bf2f((u16)hv[u]) + bf2f((u16)lv[u]),
                     cv[ks * 32 + qk8b * 8 + u], qdreg);
    }
    cur ^= 1;
  }
  qd4[qk8b][qrow] = qdreg;
  const int ps = chunk * 2 + (m0 >> 7);
  __syncthreads();                          // SA reads done; fb overlay safe
#pragma unroll
  for (int i = 0; i < 2; ++i)
#pragma unroll
    for (int j = 0; j < 2; ++j)
#pragma unroll
      for (int r = 0; r < 4; ++r)
        fb[(wm0 + i * 16 + fq * 4 + r) * 65 + wn0 + j * 16 + fm] = acc[i][j][r];
  __syncthreads();
#pragma unroll
  for (int it = 0; it < 2; ++it) {
    int unit = it * 256 + tid;              // 8 k8-cols x 64 rows
    int k8l = unit >> 6, rowl = unit & 63;
    int il = m0 + rowl;
    int jlb = jn0 + k8l * 8;
    float part = 0.f;
    u16 hs[8], ls[8];
#pragma unroll
    for (int u = 0; u < 8; ++u) {
      int jl = jlb + u;
      float v = (jl <= il) ? fb[rowl * 65 + k8l * 8 + u] * lut[il - jl] : 0.f;
      part += v;
      u16 h = f2bf(v); hs[u] = h; ls[u] = f2bf(v - bf2f(h));
    }
    atomicAdd(&rowAcc[rowl], part);
    size_t o = (size_t)(ps * 32 + (jn0 >> 3) + k8l) * 1024 +
               (size_t)((m0 & 64) + rowl) * 8;
    *(short8*)&Sgh[o] = *(short8*)hs;
    *(short8*)&Sgl[o] = *(short8*)ls;
  }
  __syncthreads();
  if (tid < 64) {
    float rs = rowAcc[tid];
    if (jn0 == 0)
      rs += exp2f((float)(m0 + tid + 1) * LOG2G) *
            (qd4[0][tid] + qd4[1][tid] + qd4[2][tid] + qd4[3][tid]);
    atomicAdd(&rsP[(size_t)b * SS + c * LL + m0 + tid], rs);
  }
}

// ---------------------------------------------------------------------------
// 5) lMatT[e][d] = sum_jl Vw[jl,e] K~[jl,d] ; R14: 64x64 tiles (grid 64x16).
//    A = V split-bf16 reg-staged (hi+lo reconstruct, wtl/denom fused) ->
//    SLABB dbuf; B = KT global->regs. Wave tile 32x32.
__global__ __launch_bounds__(256, 4) void lmat_kernel(
    const u16* __restrict__ VTh, const u16* __restrict__ VTl,
    const float* __restrict__ rsP,
    const u16* __restrict__ KTh, const u16* __restrict__ KTl,
    float* __restrict__ lMatT)
{
  const int chunk = blockIdx.x, b = chunk >> 4, c = chunk & 15;
  const int ty = blockIdx.y;
  const int m0 = (ty >> 2) * 64, n0 = (ty & 3) * 64;
  __shared__ u16 SA[2 * 8 * SLABB];
  __shared__ float swl[256];
  const int tid = threadIdx.x, lane = tid & 63, wave = tid >> 6;
  const int wm0 = (wave >> 1) * 32, wn0 = (wave & 1) * 32;
  const int fm = lane & 15, fq = lane >> 4;
  // per-jl scale = gamma^(255-jl) / max(|rsP|,1)
  swl[tid] = exp2f((float)(255 - tid) * LOG2G) /
             fmaxf(fabsf(rsP[(size_t)b * SS + c * LL + tid]), 1.0f);
  const u16* AThP = VTh + ((size_t)(b * 2 + (m0 >> 7)) * 512 + c * 32) * 1024 +
                    (size_t)(m0 & 127) * 8;
  const u16* ATlP = VTl + ((size_t)(b * 2 + (m0 >> 7)) * 512 + c * 32) * 1024 +
                    (size_t)(m0 & 127) * 8;
  const u16* BhP = KTh + ((size_t)(b * 2 + (n0 >> 7)) * 512 + c * 32) * 1024 + (size_t)(n0 & 127) * 8;
  const u16* BlP = KTl + ((size_t)(b * 2 + (n0 >> 7)) * 512 + c * 32) * 1024 + (size_t)(n0 & 127) * 8;
  const int arow = tid >> 2, ak8 = tid & 3;  // 64 rows x 4 k8, 1 unit/thread
  f32x4 acc[2][2];
#pragma unroll
  for (int i = 0; i < 2; ++i)
#pragma unroll
    for (int j = 0; j < 2; ++j) acc[i][j] = (f32x4){0.f, 0.f, 0.f, 0.f};
  short8 vh, vl;
  short8 bh[2], bl[2];
  loadB2(bh, bl, BhP, BlP, 0, wn0, fm, fq);
  {
    int off = ak8 * 1024 + arow * 8;
    vh = *(const short8*)&AThP[off];
    vl = *(const short8*)&ATlP[off];
  }
  __syncthreads();                         // swl ready
  {
    u16 hs[8], ls[8];
#pragma unroll
    for (int u = 0; u < 8; ++u) {
      float v = (bf2f((u16)vh[u]) + bf2f((u16)vl[u])) * swl[ak8 * 8 + u];
      u16 h = f2bf(v); hs[u] = h; ls[u] = f2bf(v - bf2f(h));
    }
    *(short8*)&SA[ak8 * SLABB + arow * 8] = *(short8*)hs;
    *(short8*)&SA[4 * SLABB + ak8 * SLABB + arow * 8] = *(short8*)ls;
  }
  int cur = 0;
  for (int ks = 0; ks < 8; ++ks) {
    __syncthreads();
    u16* Ac = cur ? SA + 8 * SLABB : SA;
    u16* An = cur ? SA : SA + 8 * SLABB;
    if (ks < 7) {
      int off = ((ks + 1) * 4 + ak8) * 1024 + arow * 8;
      vh = *(const short8*)&AThP[off];
      vl = *(const short8*)&ATlP[off];
    }
    mfma_64_ab(Ac, Ac + 4 * SLABB, bh, bl, wm0, fm, fq, acc);
    if (ks < 7) {
      loadB2(bh, bl, BhP, BlP, ks + 1, wn0, fm, fq);
      u16 hs[8], ls[8];
#pragma unroll
      for (int u = 0; u < 8; ++u) {
        float v = (bf2f((u16)vh[u]) + bf2f((u16)vl[u])) *
                  swl[(ks + 1) * 32 + ak8 * 8 + u];
        u16 h = f2bf(v); hs[u] = h; ls[u] = f2bf(v - bf2f(h));
      }
      *(short8*)&An[ak8 * SLABB + arow * 8] = *(short8*)hs;
      *(short8*)&An[4 * SLABB + ak8 * SLABB + arow * 8] = *(short8*)ls;
    }
    cur ^= 1;
  }
#pragma unroll
  for (int i = 0; i < 2; ++i)
#pragma unroll
    for (int j = 0; j < 2; ++j)
#pragma unroll
      for (int r = 0; r < 4; ++r) {
        int e = m0 + wm0 + i * 16 + fq * 4 + r;
        int d = n0 + wn0 + j * 16 + fm;
        lMatT[(size_t)chunk * 65536 + (size_t)e * 256 + d] = acc[i][j][r];
      }
}

// 6) carry scan -> cM packed split
__global__ __launch_bounds__(256) void combine_mat_kernel(
    const float* __restrict__ lMatT, u16* __restrict__ cMh, u16* __restrict__ cMl)
{
  const int t = blockIdx.x * 256 + threadIdx.x;
  const int b = t >> 13, rem = t & 8191;
  const int k8 = rem >> 8, e = rem & 255;
  const float gL = powf(GAMMA, (float)LL);
  float s[8] = {0.f, 0.f, 0.f, 0.f, 0.f, 0.f, 0.f, 0.f};
  for (int ch = 0; ch < 16; ++ch) {
    size_t ro = (size_t)(b * 16 + ch) * 65536 + (size_t)e * 256 + k8 * 8;
    float4 a0 = *(const float4*)&lMatT[ro];
    float4 a1 = *(const float4*)&lMatT[ro + 4];
    float vals[8] = {a0.x, a0.y, a0.z, a0.w, a1.x, a1.y, a1.z, a1.w};
    u16 hh[8], ll[8];
#pragma unroll
    for (int u = 0; u < 8; ++u) {
      u16 h = f2bf(s[u]); hh[u] = h; ll[u] = f2bf(s[u] - bf2f(h));
    }
    size_t wo = ((size_t)(((b * 16 + ch) * 2 + (e >> 7)) * 32 + k8)) * 1024 + (size_t)(e & 127) * 8;
    *(short8*)&cMh[wo] = *(short8*)hh;
    *(short8*)&cMl[wo] = *(short8*)ll;
#pragma unroll
    for (int u = 0; u < 8; ++u) s[u] = gL * s[u] + vals[u];
  }
}

// ---------------------------------------------------------------------------
// 7) out = g^(il+1) * Q~ @ cM^T + Sg @ Vd ; R15: 64x64 tiles (grid 64x16),
//    4 blocks/CU. inter: A=Q 64-row stageB64 dbuf, B=cM regs. intra: A=Sg
//    stageB64 dbuf, B=V split-bf16 reg-staged -> SLABB dbuf; nks=m0/32+2.
__global__ __launch_bounds__(256, 4) void out_kernel(
    const u16* __restrict__ Qh, const u16* __restrict__ Ql,
    const u16* __restrict__ cMh, const u16* __restrict__ cMl,
    const u16* __restrict__ Sgh, const u16* __restrict__ Sgl,
    const u16* __restrict__ VTh, const u16* __restrict__ VTl,
    const float* __restrict__ rsP,
    float* __restrict__ out)
{
  const int chunk = blockIdx.x, b = chunk >> 4, c = chunk & 15;
  const int ty = blockIdx.y;
  const int m0 = (ty >> 2) * 64, n0 = (ty & 3) * 64;
  __shared__ u16 SA[2 * 8 * SLABB];
  __shared__ u16 SB[2 * 8 * SLABB];
  __shared__ float olut[64];
  __shared__ float sdn[256];
  const int tid = threadIdx.x, lane = tid & 63, wave = tid >> 6;
  const int wm0 = (wave >> 1) * 32, wn0 = (wave & 1) * 32;
  const int fm = lane & 15, fq = lane >> 4;
  if (tid < 64) olut[tid] = exp2f((float)(m0 + tid + 1) * LOG2G);
  sdn[tid] = 1.0f / fmaxf(fabsf(rsP[(size_t)b * SS + c * LL + tid]), 1.0f);
  f32x4 acc[2][2];
#pragma unroll
  for (int i = 0; i < 2; ++i)
#pragma unroll
    for (int j = 0; j < 2; ++j) acc[i][j] = (f32x4){0.f, 0.f, 0.f, 0.f};
  int cur = 0;
  {  // inter: A = Q 64-row panel (stageB64 dbuf), B = cM rows n0.. (regs)
    const int growA = b * SS + c * LL + m0;
    const u16* AhP = Qh + (size_t)(growA >> 7) * 32768 + (size_t)(growA & 127) * 8;
    const u16* AlP = Ql + (size_t)(growA >> 7) * 32768 + (size_t)(growA & 127) * 8;
    const u16* BhP = cMh + (size_t)(chunk * 2 + (n0 >> 7)) * 32768 + (size_t)(n0 & 127) * 8;
    const u16* BlP = cMl + (size_t)(chunk * 2 + (n0 >> 7)) * 32768 + (size_t)(n0 & 127) * 8;
    short8 bh[2], bl[2];
    if (wave == 0) stageB64(AhP, SA, lane);
    if (wave == 1) stageB64(AlP, SA + 4 * SLABB, lane);
    loadB2(bh, bl, BhP, BlP, 0, wn0, fm, fq);
    for (int ks = 0; ks < 8; ++ks) {
      __syncthreads();
      u16* Ac = cur ? SA + 8 * SLABB : SA;
      u16* An = cur ? SA : SA + 8 * SLABB;
      if (ks < 7) {
        if (wave == 0) stageB64(AhP + (ks + 1) * 4096, An, lane);
        if (wave == 1) stageB64(AlP + (ks + 1) * 4096, An + 4 * SLABB, lane);
      }
      mfma_64_ab(Ac, Ac + 4 * SLABB, bh, bl, wm0, fm, fq, acc);
      if (ks < 7) loadB2(bh, bl, BhP, BlP, ks + 1, wn0, fm, fq);
      cur ^= 1;
    }
  }
  {  // intra: A = Sg 64-row panel (stageB64 dbuf), B = V split-bf16 -> SLABB
    const u16* AhP = Sgh + (size_t)(chunk * 2 + (m0 >> 7)) * 32768 + (size_t)(m0 & 127) * 8;
    const u16* AlP = Sgl + (size_t)(chunk * 2 + (m0 >> 7)) * 32768 + (size_t)(m0 & 127) * 8;
    const u16* BThP = VTh + ((size_t)(b * 2 + (n0 >> 7)) * 512 + c * 32) * 1024 + (size_t)(n0 & 127) * 8;
    const u16* BTlP = VTl + ((size_t)(b * 2 + (n0 >> 7)) * 512 + c * 32) * 1024 + (size_t)(n0 & 127) * 8;
    const int ber = tid >> 2, bk8 = tid & 3;  // 64 rows x 4 k8, 1 unit/thread
    const int nks = (m0 >> 5) + 2;            // causality: k <= m0+64
    short8 vh, vl;
    {  // prologue into buf[cur] (last read 2 steps ago -> safe)
      u16* Ac = cur ? SA + 8 * SLABB : SA;
      u16* Bc = cur ? SB + 8 * SLABB : SB;
      if (wave == 0) stageB64(AhP, Ac, lane);
      if (wave == 1) stageB64(AlP, Ac + 4 * SLABB, lane);
      int off = bk8 * 1024 + ber * 8;
      vh = *(const short8*)&BThP[off];
      vl = *(const short8*)&BTlP[off];
      // overlap acc scaling with the loads
#pragma unroll
      for (int i = 0; i < 2; ++i)
#pragma unroll
        for (int r = 0; r < 4; ++r) {
          int rl = wm0 + i * 16 + fq * 4 + r;
          float sc = olut[rl];
#pragma unroll
          for (int j = 0; j < 2; ++j) acc[i][j][r] *= sc;
        }
      u16 hs[8], ls[8];
#pragma unroll
      for (int u = 0; u < 8; ++u) {
        float v = (bf2f((u16)vh[u]) + bf2f((u16)vl[u])) * sdn[bk8 * 8 + u];
        u16 h = f2bf(v); hs[u] = h; ls[u] = f2bf(v - bf2f(h));
      }
      *(short8*)&Bc[bk8 * SLABB + ber * 8] = *(short8*)hs;
      *(short8*)&Bc[4 * SLABB + bk8 * SLABB + ber * 8] = *(short8*)ls;
    }
    for (int ks = 0; ks < nks; ++ks) {
      __syncthreads();
      u16* Ac = cur ? SA + 8 * SLABB : SA;
      u16* Bc = cur ? SB + 8 * SLABB : SB;
      u16* An = cur ? SA : SA + 8 * SLABB;
      u16* Bn = cur ? SB : SB + 8 * SLABB;
      if (ks + 1 < nks) {
        if (wave == 0) stageB64(AhP + (ks + 1) * 4096, An, lane);
        if (wave == 1) stageB64(AlP + (ks + 1) * 4096, An + 4 * SLABB, lane);
        int off = ((ks + 1) * 4 + bk8) * 1024 + ber * 8;
        vh = *(const short8*)&BThP[off];
        vl = *(const short8*)&BTlP[off];
      }
      mfma_64_bb(Ac, Ac + 4 * SLABB, Bc, Bc + 4 * SLABB, wm0, wn0, fm, fq, acc);
      if (ks + 1 < nks) {
        u16 hs[8], ls[8];
#pragma unroll
        for (int u = 0; u < 8; ++u) {
          float v = (bf2f((u16)vh[u]) + bf2f((u16)vl[u])) *
                    sdn[(ks + 1) * 32 + bk8 * 8 + u];
          u16 h = f2bf(v); hs[u] = h; ls[u] = f2bf(v - bf2f(h));
        }
        *(short8*)&Bn[bk8 * SLABB + ber * 8] = *(short8*)hs;
        *(short8*)&Bn[4 * SLABB + bk8 * SLABB + ber * 8] = *(short8*)ls;
      }
      cur ^= 1;
    }
  }
#pragma unroll
  for (int i = 0; i < 2; ++i)
#pragma unroll
    for (int j = 0; j < 2; ++j)
#pragma unroll
      for (int r = 0; r < 4; ++r) {
        int il = m0 + wm0 + i * 16 + fq * 4 + r;
        int e = n0 + wn0 + j * 16 + fm;
        out[(size_t)(b * SS + c * LL + il) * DD + e] = acc[i][j][r];
      }
}

// ---------------------------------------------------------------------------
extern "C" void kernel_launch(void* const* d_in, const int* in_sizes, int n_in,
                              void* d_out, int out_size, void* d_ws, size_t ws_size,
                              hipStream_t stream) {
  const float* xq = (const float*)d_in[0];
  const float* xk = (const float*)d_in[1];
  const float* xv = (const float*)d_in[2];
  const float* Wq = (const float*)d_in[3];
  const float* bq = (const float*)d_in[4];
  const float* Wk = (const float*)d_in[5];
  const float* bk = (const float*)d_in[6];
  const float* Wv = (const float*)d_in[7];
  const float* bv = (const float*)d_in[8];
  float* out = (float*)d_out;

  char* p = (char*)d_ws;
  const size_t H16 = (size_t)BB * SS * DD * 2;  // 8 MB
  u16* Qh   = (u16*)(p + 0 * H16);  u16* Ql   = (u16*)(p + 1 * H16);
  u16* Kh   = (u16*)(p + 2 * H16);  u16* Kl   = (u16*)(p + 3 * H16);
  u16* KTh  = (u16*)(p + 4 * H16);  u16* KTl  = (u16*)(p + 5 * H16);
  u16* VTh  = (u16*)(p + 6 * H16);  u16* VTl  = (u16*)(p + 7 * H16);
  u16* Sgh  = (u16*)(p + 10 * H16); u16* Sgl  = (u16*)(p + 11 * H16);
  u16* cMh  = (u16*)(p + 12 * H16); u16* cMl  = (u16*)(p + 13 * H16);
  float* lMatT = (float*)(p + 14 * H16);
  u16* Wth = (u16*)(p + 18 * H16);
  u16* Wtl = (u16*)(p + 18 * H16 + 3 * DD * DD * 2);
  float* rsP  = (float*)(p + 18 * H16 + 6 * DD * DD * 2);
  float* lVec = rsP + (size_t)BB * SS;

  init_pack_kernel<<<dim3(3, 16), 256, 0, stream>>>(Wq, Wk, Wv, Wth, Wtl, rsP, lVec);
  proj_kernel<<<dim3(BB * SS / 32, 1, 3), 256, 0, stream>>>(
      xq, xk, xv, Wth, Wtl, bq, bk, bv, Qh, Ql, Kh, Kl, KTh, KTl, VTh, VTl, lVec);
  scores_kernel<<<dim3(BB * NCH, 10), 256, 0, stream>>>(
      Qh, Ql, Kh, Kl, lVec, Sgh, Sgl, rsP);
  lmat_kernel<<<dim3(BB * NCH, 16), 256, 0, stream>>>(VTh, VTl, rsP, KTh, KTl, lMatT);
  combine_mat_kernel<<<128, 256, 0, stream>>>(lMatT, cMh, cMl);
  out_kernel<<<dim3(BB * NCH, 16), 256, 0, stream>>>(
      Qh, Ql, cMh, cMl, Sgh, Sgl, VTh, VTl, rsP, out);
}

// Round 17
// 195.512 us; speedup vs baseline: 1.0515x; 1.0515x over previous
//
#include <hip/hip_runtime.h>
#include <math.h>

// Retention (B=4, S=4096, D=256): chunkwise, split-bf16 MFMA, packed k8-slab
// operands.
// R1-R15: see history. R15 = 194.9us (64-row retile of scores/lmat/out;
//   proj BM=64 pn-merged).
// R16: FAILED (proj BM=32 halved MFMA/barrier; per-block efficiency lost
//   more than occupancy gained). Lesson: retile only pays when grid-starved
//   AND per-block amortization survives.
// R17: proj reverted to R15 form (BM=64, (256,3), verified 40.5us).
#define BB 4
#define SS 4096
#define DD 256
#define LL 256
#define NCH 16
#define GAMMA 0.9865f
#define LOG2G (-0.019609034f)   // log2(0.9865)
#define INV1MG 74.07407407f     // 1/(1-gamma)
#define SLAB 1032               // padded LDS slab stride (u16), 128-row panels
#define SLABB 520               // padded LDS slab stride (u16), 64-row panels

typedef __attribute__((ext_vector_type(8))) short short8;
typedef __attribute__((ext_vector_type(4))) float f32x4;
typedef unsigned short u16;
typedef unsigned int u32;

__device__ __forceinline__ u16 f2bf(float f) {
  union { float f; unsigned u; } v; v.f = f;
  unsigned r = v.u + 0x7FFFu + ((v.u >> 16) & 1u);
  return (u16)(r >> 16);
}
__device__ __forceinline__ float bf2f(u16 h) {
  union { unsigned u; float f; } v; v.u = ((unsigned)h) << 16; return v.f;
}

__device__ __forceinline__ void gll16(const u16* g, u16* l) {
  __builtin_amdgcn_global_load_lds(
      (const __attribute__((address_space(1))) u32*)g,
      (__attribute__((address_space(3))) u32*)l, 16, 0, 0);
}
// stage one BK=32 k-step of 64 rows from a 128-row panel (row offset folded
// into g by caller): 4 slabs x 64 rows, SLABB stride
__device__ __forceinline__ void stageB64(const u16* g, u16* l, int lane) {
#pragma unroll
  for (int i = 0; i < 4; ++i)
    gll16(g + i * 1024 + lane * 8, l + i * SLABB);
}

// 64-row A from LDS (SLABB slabs), B regs[4]; 64x64 per wave (proj R13)
__device__ __forceinline__ void mfma_step_regB64(
    const u16* Ah, const u16* Al, const short8 bh[4], const short8 bl[4],
    int fm, int fq, f32x4 acc[4][4])
{
  const int ka = fq * SLABB;
  short8 ah[4], al[4];
#pragma unroll
  for (int i = 0; i < 4; ++i) {
    ah[i] = *(const short8*)&Ah[ka + (i * 16 + fm) * 8];
    al[i] = *(const short8*)&Al[ka + (i * 16 + fm) * 8];
  }
#pragma unroll
  for (int j = 0; j < 4; ++j)
#pragma unroll
    for (int i = 0; i < 4; ++i) {
      acc[i][j] = __builtin_amdgcn_mfma_f32_16x16x32_bf16(al[i], bh[j], acc[i][j], 0, 0, 0);
      acc[i][j] = __builtin_amdgcn_mfma_f32_16x16x32_bf16(ah[i], bl[j], acc[i][j], 0, 0, 0);
      acc[i][j] = __builtin_amdgcn_mfma_f32_16x16x32_bf16(ah[i], bh[j], acc[i][j], 0, 0, 0);
    }
}

// 64-row-A tile (SLABB stride), wave does 32x32: A rows wm0+{0,16}, B regs[2]
__device__ __forceinline__ void mfma_64_ab(
    const u16* Ah, const u16* Al, const short8 bh[2], const short8 bl[2],
    int wm0, int fm, int fq, f32x4 acc[2][2])
{
  const int ka = fq * SLABB;
  short8 ah[2], al[2];
#pragma unroll
  for (int i = 0; i < 2; ++i) {
    ah[i] = *(const short8*)&Ah[ka + (wm0 + i * 16 + fm) * 8];
    al[i] = *(const short8*)&Al[ka + (wm0 + i * 16 + fm) * 8];
  }
#pragma unroll
  for (int j = 0; j < 2; ++j)
#pragma unroll
    for (int i = 0; i < 2; ++i) {
      acc[i][j] = __builtin_amdgcn_mfma_f32_16x16x32_bf16(al[i], bh[j], acc[i][j], 0, 0, 0);
      acc[i][j] = __builtin_amdgcn_mfma_f32_16x16x32_bf16(ah[i], bl[j], acc[i][j], 0, 0, 0);
      acc[i][j] = __builtin_amdgcn_mfma_f32_16x16x32_bf16(ah[i], bh[j], acc[i][j], 0, 0, 0);
    }
}

// 64-row tile, A and B both from SLABB-stride LDS, wave 32x32 (out-intra)
__device__ __forceinline__ void mfma_64_bb(
    const u16* Ah, const u16* Al, const u16* Bh, const u16* Bl,
    int wm0, int wn0, int fm, int fq, f32x4 acc[2][2])
{
  const int ka = fq * SLABB;
  short8 ah[2], al[2];
#pragma unroll
  for (int i = 0; i < 2; ++i) {
    ah[i] = *(const short8*)&Ah[ka + (wm0 + i * 16 + fm) * 8];
    al[i] = *(const short8*)&Al[ka + (wm0 + i * 16 + fm) * 8];
  }
#pragma unroll
  for (int j = 0; j < 2; ++j) {
    short8 bh = *(const short8*)&Bh[ka + (wn0 + j * 16 + fm) * 8];
    short8 bl = *(const short8*)&Bl[ka + (wn0 + j * 16 + fm) * 8];
#pragma unroll
    for (int i = 0; i < 2; ++i) {
      acc[i][j] = __builtin_amdgcn_mfma_f32_16x16x32_bf16(al[i], bh, acc[i][j], 0, 0, 0);
      acc[i][j] = __builtin_amdgcn_mfma_f32_16x16x32_bf16(ah[i], bl, acc[i][j], 0, 0, 0);
      acc[i][j] = __builtin_amdgcn_mfma_f32_16x16x32_bf16(ah[i], bh, acc[i][j], 0, 0, 0);
    }
  }
}

// load a wave's 64-row-panel B-fragments (2 col-groups, hi+lo) from global.
__device__ __forceinline__ void loadB2(short8 bh[2], short8 bl[2],
    const u16* BhP, const u16* BlP, int ks, int wn0, int fm, int fq)
{
  const int base = ks * 4096 + fq * 1024;
#pragma unroll
  for (int j = 0; j < 2; ++j) {
    int o = base + (wn0 + j * 16 + fm) * 8;
    bh[j] = *(const short8*)&BhP[o];
    bl[j] = *(const short8*)&BlP[o];
  }
}

// ---------------------------------------------------------------------------
// 0) pack W^T slabs (hi/lo) + zero rsP/lVec accumulators. grid (3, 16).
__global__ __launch_bounds__(256) void init_pack_kernel(
    const float* __restrict__ Wq, const float* __restrict__ Wk, const float* __restrict__ Wv,
    u16* __restrict__ Wth, u16* __restrict__ Wtl,
    float* __restrict__ rsP, float* __restrict__ lVec)
{
  const int which = blockIdx.x;
  const int it = blockIdx.y;
  const int t = threadIdx.x;
  if (which == 0) {
    *(float4*)&rsP[(size_t)(it * 256 + t) * 4] = (float4){0.f, 0.f, 0.f, 0.f};
  } else if (which == 1) {
    *(float4*)&lVec[(size_t)(it * 256 + t) * 4] = (float4){0.f, 0.f, 0.f, 0.f};
  }
  const float* W = which == 0 ? Wq : (which == 1 ? Wk : Wv);
  for (int pn = 0; pn < 2; ++pn) {
    int pos = it * 256 + t;
    int k8 = pos >> 7, r = pos & 127;
    u16 hs[8], ls[8];
#pragma unroll
    for (int u = 0; u < 8; ++u) {
      float x = W[(size_t)(k8 * 8 + u) * DD + pn * 128 + r];
      u16 h = f2bf(x); hs[u] = h; ls[u] = f2bf(x - bf2f(h));
    }
    size_t o = ((size_t)((which * 2 + pn) * 32 + k8)) * 1024 + (size_t)r * 8;
    *(short8*)&Wth[o] = *(short8*)hs;
    *(short8*)&Wtl[o] = *(short8*)ls;
  }
}

// ---------------------------------------------------------------------------
// 1) projections (R13/R15 form): BM=64 x BN=256, pn merged. A: fp32 X
//    (64x32/step) reg-prefetched, split once into SLABB dbuf. B: W^T frags
//    in regs per wave (4 col-groups over its 64-col strip). 4 quarter-width
//    epilogues. 3 blocks/CU.
__global__ __launch_bounds__(256, 3) void proj_kernel(
    const float* __restrict__ xq, const float* __restrict__ xk, const float* __restrict__ xv,
    const u16* __restrict__ Wth, const u16* __restrict__ Wtl,
    const float* __restrict__ bq, const float* __restrict__ bk_, const float* __restrict__ bv,
    u16* __restrict__ Qh, u16* __restrict__ Ql,
    u16* __restrict__ Kh, u16* __restrict__ Kl,
    u16* __restrict__ KTh, u16* __restrict__ KTl,
    u16* __restrict__ VTh, u16* __restrict__ VTl,
    float* __restrict__ lVec)
{
  const int which = blockIdx.z;
  const float* bias = which == 0 ? bq : (which == 1 ? bk_ : bv);
  const int m0 = blockIdx.x * 64;
  __shared__ u16 SM[16 * SLABB];          // A dbuf (2 x (4hi+4lo) SLABB slabs)
  __shared__ float rsc[64];
  __shared__ float wlut[64];
  __shared__ float kacc[64];
  float* fb = (float*)SM;                 // 64x65 fp32 bounce (epilogue only)
  const int tid = threadIdx.x, lane = tid & 63, wave = tid >> 6;
  const int wn0g = wave * 64;             // wave's global col strip
  const int fm = lane & 15, fq = lane >> 4;
  if (which == 1 && tid < 64) {
    int sb = (m0 & (SS - 1)) + tid;
    rsc[tid] = rsqrtf((1.0f - exp2f((float)(sb + 1) * LOG2G)) * INV1MG);
    wlut[tid] = exp2f((float)(255 - ((m0 & (LL - 1)) + tid)) * LOG2G);
    kacc[tid] = 0.f;
  }
  const float* XP = (which == 0 ? xq : (which == 1 ? xk : xv)) + (size_t)m0 * DD;
  const int pnw = wn0g >> 7, wl = wn0g & 127;
  const u16* WhP = Wth + (size_t)((which * 2 + pnw) * 32) * 1024;
  const u16* WlP = Wtl + (size_t)((which * 2 + pnw) * 32) * 1024;
  const int arow = tid >> 2, ak8 = tid & 3;  // 64 rows x 4 k8, 1 unit/thread
  f32x4 acc[4][4];
#pragma unroll
  for (int i = 0; i < 4; ++i)
#pragma unroll
    for (int j = 0; j < 4; ++j) acc[i][j] = (f32x4){0.f, 0.f, 0.f, 0.f};
  float xs[8];
  short8 bh[4], bl[4];
  // prologue: W(0) into regs, X(0) into buffer 0
  {
    const int base = fq * 1024;
#pragma unroll
    for (int j = 0; j < 4; ++j) {
      int o = base + (wl + j * 16 + fm) * 8;
      bh[j] = *(const short8*)&WhP[o];
      bl[j] = *(const short8*)&WlP[o];
    }
  }
  {
    const float* src = XP + (size_t)arow * DD + ak8 * 8;
    *(float4*)&xs[0] = *(const float4*)src;
    *(float4*)&xs[4] = *(const float4*)(src + 4);
    u16 hs[8], ls[8];
#pragma unroll
    for (int u = 0; u < 8; ++u) {
      u16 h = f2bf(xs[u]); hs[u] = h; ls[u] = f2bf(xs[u] - bf2f(h));
    }
    *(short8*)&SM[ak8 * SLABB + arow * 8] = *(short8*)hs;
    *(short8*)&SM[4 * SLABB + ak8 * SLABB + arow * 8] = *(short8*)ls;
  }
  int cur = 0;
  for (int ks = 0; ks < 8; ++ks) {
    __syncthreads();                       // buf[cur] ready
    u16* Ac = SM + cur * 8 * SLABB;
    u16* An = SM + (cur ^ 1) * 8 * SLABB;
    if (ks < 7) {
      const float* src = XP + (size_t)arow * DD + (ks + 1) * 32 + ak8 * 8;
      *(float4*)&xs[0] = *(const float4*)src;
      *(float4*)&xs[4] = *(const float4*)(src + 4);
    }
    mfma_step_regB64(Ac, Ac + 4 * SLABB, bh, bl, fm, fq, acc);
    if (ks < 7) {
      const int base = (ks + 1) * 4096 + fq * 1024;
#pragma unroll
      for (int j = 0; j < 4; ++j) {        // prefetch next W frags
        int o = base + (wl + j * 16 + fm) * 8;
        bh[j] = *(const short8*)&WhP[o];
        bl[j] = *(const short8*)&WlP[o];
      }
      u16 hs[8], ls[8];
#pragma unroll
      for (int u = 0; u < 8; ++u) {
        u16 h = f2bf(xs[u]); hs[u] = h; ls[u] = f2bf(xs[u] - bf2f(h));
      }
      *(short8*)&An[ak8 * SLABB + arow * 8] = *(short8*)hs;
      *(short8*)&An[4 * SLABB + ak8 * SLABB + arow * 8] = *(short8*)ls;
    }
    cur ^= 1;
  }
  const int b = m0 >> 12, sbb = m0 & (SS - 1);
  for (int p = 0; p < 4; ++p) {            // quarter-width column passes
    __syncthreads();
    if (wn0g == p * 64) {                  // owning wave bounces acc -> fb
#pragma unroll
      for (int i = 0; i < 4; ++i)
#pragma unroll
        for (int j = 0; j < 4; ++j)
#pragma unroll
          for (int r = 0; r < 4; ++r)
            fb[(i * 16 + fq * 4 + r) * 65 + j * 16 + fm] = acc[i][j][r];
    }
    __syncthreads();
    if (which == 0) {
#pragma unroll
      for (int it = 0; it < 2; ++it) {
        int unit = it * 256 + tid;         // 8 k8 x 64 rows
        int k8l = unit >> 6, row = unit & 63;
        int gc0 = p * 64 + k8l * 8;
        u16 hs[8], ls[8];
#pragma unroll
        for (int u = 0; u < 8; ++u) {
          float v = (fb[row * 65 + k8l * 8 + u] + bias[gc0 + u]) * (1.f / 16.f);
          u16 h = f2bf(v); hs[u] = h; ls[u] = f2bf(v - bf2f(h));
        }
        size_t o = (size_t)(m0 >> 7) * 32768 + (size_t)(p * 8 + k8l) * 1024 +
                   (size_t)((m0 & 64) + row) * 8;
        *(short8*)&Qh[o] = *(short8*)hs;
        *(short8*)&Ql[o] = *(short8*)ls;
      }
    } else if (which == 1) {
#pragma unroll
      for (int it = 0; it < 2; ++it) {     // K (row-major panel)
        int unit = it * 256 + tid;
        int k8l = unit >> 6, row = unit & 63;
        int gc0 = p * 64 + k8l * 8;
        u16 hs[8], ls[8];
#pragma unroll
        for (int u = 0; u < 8; ++u) {
          float v = (fb[row * 65 + k8l * 8 + u] + bias[gc0 + u]) * rsc[row];
          u16 h = f2bf(v); hs[u] = h; ls[u] = f2bf(v - bf2f(h));
        }
        size_t o = (size_t)(m0 >> 7) * 32768 + (size_t)(p * 8 + k8l) * 1024 +
                   (size_t)((m0 & 64) + row) * 8;
        *(short8*)&Kh[o] = *(short8*)hs;
        *(short8*)&Kl[o] = *(short8*)ls;
      }
      float kpart = 0.f;
#pragma unroll
      for (int it = 0; it < 2; ++it) {     // KT (col-major packed) + lVec
        int unit = it * 256 + tid;
        int dl = unit & 63, s8l = unit >> 6;
        int gcolg = p * 64 + dl;
        float bs = bias[gcolg];
        u16 hs[8], ls[8];
#pragma unroll
        for (int u = 0; u < 8; ++u) {
          int row = s8l * 8 + u;
          float v = (fb[row * 65 + dl] + bs) * rsc[row];
          kpart = fmaf(v, wlut[row], kpart);
          u16 h = f2bf(v); hs[u] = h; ls[u] = f2bf(v - bf2f(h));
        }
        int sb0 = sbb + s8l * 8;
        size_t o = ((size_t)(b * 2 + (gcolg >> 7)) * 512 + (sb0 >> 3)) * 1024 + (size_t)(gcolg & 127) * 8;
        *(short8*)&KTh[o] = *(short8*)hs;
        *(short8*)&KTl[o] = *(short8*)ls;
      }
      atomicAdd(&kacc[tid & 63], kpart);
      __syncthreads();
      if (tid < 64) {
        int c = sbb >> 8;
        atomicAdd(&lVec[(size_t)(b * NCH + c) * DD + p * 64 + tid], kacc[tid]);
        kacc[tid] = 0.f;
      }
    } else {  // V: split-bf16, KT-packed layout
#pragma unroll
      for (int it = 0; it < 2; ++it) {
        int unit = it * 256 + tid;
        int dl = unit & 63, s8l = unit >> 6;
        int gcolg = p * 64 + dl;
        float bs = bias[gcolg];
        u16 hs[8], ls[8];
#pragma unroll
        for (int u = 0; u < 8; ++u) {
          float v = fb[(s8l * 8 + u) * 65 + dl] + bs;
          u16 h = f2bf(v); hs[u] = h; ls[u] = f2bf(v - bf2f(h));
        }
        int sb0 = sbb + s8l * 8;
        size_t o = ((size_t)(b * 2 + (gcolg >> 7)) * 512 + (sb0 >> 3)) * 1024 + (size_t)(gcolg & 127) * 8;
        *(short8*)&VTh[o] = *(short8*)hs;
        *(short8*)&VTl[o] = *(short8*)ls;
      }
    }
  }
}

// ---------------------------------------------------------------------------
// 3) Sg = mask*(Q~.K~)*g^(il-jl); fused rowsum + Q.cVec dot -> rsP atomics.
//    R14: 64x64 tiles, causal triangle grid (64 x 10). A = Q 64-row half
//    panel via stageB64 dbuf; B = K frags global->regs. Wave tile 32x32.
__global__ __launch_bounds__(256, 4) void scores_kernel(
    const u16* __restrict__ Qh, const u16* __restrict__ Ql,
    const u16* __restrict__ Kh, const u16* __restrict__ Kl,
    const float* __restrict__ lVec, u16* __restrict__ Sgh, u16* __restrict__ Sgl,
    float* __restrict__ rsP)
{
  const int chunk = blockIdx.x, b = chunk >> 4, c = chunk & 15;
  const int y = blockIdx.y;
  const int mi = (y >= 6) ? 3 : (y >= 3) ? 2 : (y >= 1) ? 1 : 0;
  const int ji = y - mi * (mi + 1) / 2;
  const int m0 = mi * 64, jn0 = ji * 64;
  __shared__ u16 SA[2 * 8 * SLABB];
  __shared__ float cv[256], lut[256], rowAcc[64], qd4[4][64];
  float* fb = (float*)SA;  // 64x65 fp32 = 16640B = |SA| (epilogue only)
  const int tid = threadIdx.x, lane = tid & 63, wave = tid >> 6;
  const int wm0 = (wave >> 1) * 32, wn0 = (wave & 1) * 32;
  const int fm = lane & 15, fq = lane >> 4;
  if (jn0 == 0) {  // inline prefix scan: cv = sum_{cp<c} gL^(c-1-cp) lVec[cp]
    const float gL = exp2f((float)LL * LOG2G);
    float s = 0.f;
    for (int cp = 0; cp < c; ++cp)
      s = fmaf(gL, s, lVec[(size_t)(b * NCH + cp) * DD + tid]);
    cv[tid] = s;
  }
  lut[tid] = exp2f((float)tid * LOG2G);
  if (tid < 64) rowAcc[tid] = 0.f;
  const int growA = b * SS + c * LL + m0;
  const int growB = b * SS + c * LL + jn0;
  const u16* QhP = Qh + (size_t)(growA >> 7) * 32768 + (size_t)(growA & 127) * 8;
  const u16* QlP = Ql + (size_t)(growA >> 7) * 32768 + (size_t)(growA & 127) * 8;
  const u16* KhP = Kh + (size_t)(growB >> 7) * 32768 + (size_t)(growB & 127) * 8;
  const u16* KlP = Kl + (size_t)(growB >> 7) * 32768 + (size_t)(growB & 127) * 8;
  f32x4 acc[2][2];
#pragma unroll
  for (int i = 0; i < 2; ++i)
#pragma unroll
    for (int j = 0; j < 2; ++j) acc[i][j] = (f32x4){0.f, 0.f, 0.f, 0.f};
  float qdreg = 0.f;
  const int qrow = tid & 63, qk8b = tid >> 6;  // 64 rows x 4 k8
  short8 bh[2], bl[2];
  if (wave == 0) stageB64(QhP, SA, lane);
  if (wave == 1) stageB64(QlP, SA + 4 * SLABB, lane);
  loadB2(bh, bl, KhP, KlP, 0, wn0, fm, fq);
  int cur = 0;
  for (int ks = 0; ks < 8; ++ks) {
    __syncthreads();
    u16* Ac = cur ? SA + 8 * SLABB : SA;
    u16* An = cur ? SA : SA + 8 * SLABB;
    if (ks < 7) {
      if (wave == 0) stageB64(QhP + (ks + 1) * 4096, An, lane);
      if (wave == 1) stageB64(QlP + (ks + 1) * 4096, An + 4 * SLABB, lane);
    }
    mfma_64_ab(Ac, Ac + 4 * SLABB, bh, bl, wm0, fm, fq, acc);
    if (ks < 7) loadB2(bh, bl, KhP, KlP, ks + 1, wn0, fm, fq);
    if (jn0 == 0) {
      short8 hv = *(const short8*)&Ac[qk8b * SLABB + qrow * 8];
      short8 lv = *(const short8*)&Ac[4 * SLABB + qk8b * SLABB + qrow * 8];
#pragma unroll
      for (int u = 0; u < 8; ++u)
        qdreg = fmaf(bf2f((u16)hv[u]) + bf2f((u16)lv[u]),
                     cv[ks * 32 + qk8b * 8 + u], qdreg);
    }
    cur ^= 1;
  }
  qd4[qk8b][qrow] = qdreg;
  const int ps = chunk * 2 + (m0 >> 7);
  __syncthreads();                          // SA reads done; fb overlay safe
#pragma unroll
  for (int i = 0; i < 2; ++i)
#pragma unroll
    for (int j = 0; j < 2; ++j)
#pragma unroll
      for (int r = 0; r < 4; ++r)
        fb[(wm0 + i * 16 + fq * 4 + r) * 65 + wn0 + j * 16 + fm] = acc[i][j][r];
  __syncthreads();
#pragma unroll
  for (int it = 0; it < 2; ++it) {
    int unit = it * 256 + tid;              // 8 k8-cols x 64 rows
    int k8l = unit >> 6, rowl = unit & 63;
    int il = m0 + rowl;
    int jlb = jn0 + k8l * 8;
    float part = 0.f;
    u16 hs[8], ls[8];
#pragma unroll
    for (int u = 0; u < 8; ++u) {
      int jl = jlb + u;
      float v = (jl <= il) ? fb[rowl * 65 + k8l * 8 + u] * lut[il - jl] : 0.f;
      part += v;
      u16 h = f2bf(v); hs[u] = h; ls[u] = f2bf(v - bf2f(h));
    }
    atomicAdd(&rowAcc[rowl], part);
    size_t o = (size_t)(ps * 32 + (jn0 >> 3) + k8l) * 1024 +
               (size_t)((m0 & 64) + rowl) * 8;
    *(short8*)&Sgh[o] = *(short8*)hs;
    *(short8*)&Sgl[o] = *(short8*)ls;
  }
  __syncthreads();
  if (tid < 64) {
    float rs = rowAcc[tid];
    if (jn0 == 0)
      rs += exp2f((float)(m0 + tid + 1) * LOG2G) *
            (qd4[0][tid] + qd4[1][tid] + qd4[2][tid] + qd4[3][tid]);
    atomicAdd(&rsP[(size_t)b * SS + c * LL + m0 + tid], rs);
  }
}

// ---------------------------------------------------------------------------
// 5) lMatT[e][d] = sum_jl Vw[jl,e] K~[jl,d] ; R14: 64x64 tiles (grid 64x16).
//    A = V split-bf16 reg-staged (hi+lo reconstruct, wtl/denom fused) ->
//    SLABB dbuf; B = KT global->regs. Wave tile 32x32.
__global__ __launch_bounds__(256, 4) void lmat_kernel(
    const u16* __restrict__ VTh, const u16* __restrict__ VTl,
    const float* __restrict__ rsP,
    const u16* __restrict__ KTh, const u16* __restrict__ KTl,
    float* __restrict__ lMatT)
{
  const int chunk = blockIdx.x, b = chunk >> 4, c = chunk & 15;
  const int ty = blockIdx.y;
  const int m0 = (ty >> 2) * 64, n0 = (ty & 3) * 64;
  __shared__ u16 SA[2 * 8 * SLABB];
  __shared__ float swl[256];
  const int tid = threadIdx.x, lane = tid & 63, wave = tid >> 6;
  const int wm0 = (wave >> 1) * 32, wn0 = (wave & 1) * 32;
  const int fm = lane & 15, fq = lane >> 4;
  // per-jl scale = gamma^(255-jl) / max(|rsP|,1)
  swl[tid] = exp2f((float)(255 - tid) * LOG2G) /
             fmaxf(fabsf(rsP[(size_t)b * SS + c * LL + tid]), 1.0f);
  const u16* AThP = VTh + ((size_t)(b * 2 + (m0 >> 7)) * 512 + c * 32) * 1024 +
                    (size_t)(m0 & 127) * 8;
  const u16* ATlP = VTl + ((size_t)(b * 2 + (m0 >> 7)) * 512 + c * 32) * 1024 +
                    (size_t)(m0 & 127) * 8;
  const u16* BhP = KTh + ((size_t)(b * 2 + (n0 >> 7)) * 512 + c * 32) * 1024 + (size_t)(n0 & 127) * 8;
  const u16* BlP = KTl + ((size_t)(b * 2 + (n0 >> 7)) * 512 + c * 32) * 1024 + (size_t)(n0 & 127) * 8;
  const int arow = tid >> 2, ak8 = tid & 3;  // 64 rows x 4 k8, 1 unit/thread
  f32x4 acc[2][2];
#pragma unroll
  for (int i = 0; i < 2; ++i)
#pragma unroll
    for (int j = 0; j < 2; ++j) acc[i][j] = (f32x4){0.f, 0.f, 0.f, 0.f};
  short8 vh, vl;
  short8 bh[2], bl[2];
  loadB2(bh, bl, BhP, BlP, 0, wn0, fm, fq);
  {
    int off = ak8 * 1024 + arow * 8;
    vh = *(const short8*)&AThP[off];
    vl = *(const short8*)&ATlP[off];
  }
  __syncthreads();                         // swl ready
  {
    u16 hs[8], ls[8];
#pragma unroll
    for (int u = 0; u < 8; ++u) {
      float v = (bf2f((u16)vh[u]) + bf2f((u16)vl[u])) * swl[ak8 * 8 + u];
      u16 h = f2bf(v); hs[u] = h; ls[u] = f2bf(v - bf2f(h));
    }
    *(short8*)&SA[ak8 * SLABB + arow * 8] = *(short8*)hs;
    *(short8*)&SA[4 * SLABB + ak8 * SLABB + arow * 8] = *(short8*)ls;
  }
  int cur = 0;
  for (int ks = 0; ks < 8; ++ks) {
    __syncthreads();
    u16* Ac = cur ? SA + 8 * SLABB : SA;
    u16* An = cur ? SA : SA + 8 * SLABB;
    if (ks < 7) {
      int off = ((ks + 1) * 4 + ak8) * 1024 + arow * 8;
      vh = *(const short8*)&AThP[off];
      vl = *(const short8*)&ATlP[off];
    }
    mfma_64_ab(Ac, Ac + 4 * SLABB, bh, bl, wm0, fm, fq, acc);
    if (ks < 7) {
      loadB2(bh, bl, BhP, BlP, ks + 1, wn0, fm, fq);
      u16 hs[8], ls[8];
#pragma unroll
      for (int u = 0; u < 8; ++u) {
        float v = (bf2f((u16)vh[u]) + bf2f((u16)vl[u])) *
                  swl[(ks + 1) * 32 + ak8 * 8 + u];
        u16 h = f2bf(v); hs[u] = h; ls[u] = f2bf(v - bf2f(h));
      }
      *(short8*)&An[ak8 * SLABB + arow * 8] = *(short8*)hs;
      *(short8*)&An[4 * SLABB + ak8 * SLABB + arow * 8] = *(short8*)ls;
    }
    cur ^= 1;
  }
#pragma unroll
  for (int i = 0; i < 2; ++i)
#pragma unroll
    for (int j = 0; j < 2; ++j)
#pragma unroll
      for (int r = 0; r < 4; ++r) {
        int e = m0 + wm0 + i * 16 + fq * 4 + r;
        int d = n0 + wn0 + j * 16 + fm;
        lMatT[(size_t)chunk * 65536 + (size_t)e * 256 + d] = acc[i][j][r];
      }
}

// 6) carry scan -> cM packed split
__global__ __launch_bounds__(256) void combine_mat_kernel(
    const float* __restrict__ lMatT, u16* __restrict__ cMh, u16* __restrict__ cMl)
{
  const int t = blockIdx.x * 256 + threadIdx.x;
  const int b = t >> 13, rem = t & 8191;
  const int k8 = rem >> 8, e = rem & 255;
  const float gL = powf(GAMMA, (float)LL);
  float s[8] = {0.f, 0.f, 0.f, 0.f, 0.f, 0.f, 0.f, 0.f};
  for (int ch = 0; ch < 16; ++ch) {
    size_t ro = (size_t)(b * 16 + ch) * 65536 + (size_t)e * 256 + k8 * 8;
    float4 a0 = *(const float4*)&lMatT[ro];
    float4 a1 = *(const float4*)&lMatT[ro + 4];
    float vals[8] = {a0.x, a0.y, a0.z, a0.w, a1.x, a1.y, a1.z, a1.w};
    u16 hh[8], ll[8];
#pragma unroll
    for (int u = 0; u < 8; ++u) {
      u16 h = f2bf(s[u]); hh[u] = h; ll[u] = f2bf(s[u] - bf2f(h));
    }
    size_t wo = ((size_t)(((b * 16 + ch) * 2 + (e >> 7)) * 32 + k8)) * 1024 + (size_t)(e & 127) * 8;
    *(short8*)&cMh[wo] = *(short8*)hh;
    *(short8*)&cMl[wo] = *(short8*)ll;
#pragma unroll
    for (int u = 0; u < 8; ++u) s[u] = gL * s[u] + vals[u];
  }
}

// ---------------------------------------------------------------------------
// 7) out = g^(il+1) * Q~ @ cM^T + Sg @ Vd ; R15: 64x64 tiles (grid 64x16),
//    4 blocks/CU. inter: A=Q 64-row stageB64 dbuf, B=cM regs. intra: A=Sg
//    stageB64 dbuf, B=V split-bf16 reg-staged -> SLABB dbuf; nks=m0/32+2.
__global__ __launch_bounds__(256, 4) void out_kernel(
    const u16* __restrict__ Qh, const u16* __restrict__ Ql,
    const u16* __restrict__ cMh, const u16* __restrict__ cMl,
    const u16* __restrict__ Sgh, const u16* __restrict__ Sgl,
    const u16* __restrict__ VTh, const u16* __restrict__ VTl,
    const float* __restrict__ rsP,
    float* __restrict__ out)
{
  const int chunk = blockIdx.x, b = chunk >> 4, c = chunk & 15;
  const int ty = blockIdx.y;
  const int m0 = (ty >> 2) * 64, n0 = (ty & 3) * 64;
  __shared__ u16 SA[2 * 8 * SLABB];
  __shared__ u16 SB[2 * 8 * SLABB];
  __shared__ float olut[64];
  __shared__ float sdn[256];
  const int tid = threadIdx.x, lane = tid & 63, wave = tid >> 6;
  const int wm0 = (wave >> 1) * 32, wn0 = (wave & 1) * 32;
  const int fm = lane & 15, fq = lane >> 4;
  if (tid < 64) olut[tid] = exp2f((float)(m0 + tid + 1) * LOG2G);
  sdn[tid] = 1.0f / fmaxf(fabsf(rsP[(size_t)b * SS + c * LL + tid]), 1.0f);
  f32x4 acc[2][2];
#pragma unroll
  for (int i = 0; i < 2; ++i)
#pragma unroll
    for (int j = 0; j < 2; ++j) acc[i][j] = (f32x4){0.f, 0.f, 0.f, 0.f};
  int cur = 0;
  {  // inter: A = Q 64-row panel (stageB64 dbuf), B = cM rows n0.. (regs)
    const int growA = b * SS + c * LL + m0;
    const u16* AhP = Qh + (size_t)(growA >> 7) * 32768 + (size_t)(growA & 127) * 8;
    const u16* AlP = Ql + (size_t)(growA >> 7) * 32768 + (size_t)(growA & 127) * 8;
    const u16* BhP = cMh + (size_t)(chunk * 2 + (n0 >> 7)) * 32768 + (size_t)(n0 & 127) * 8;
    const u16* BlP = cMl + (size_t)(chunk * 2 + (n0 >> 7)) * 32768 + (size_t)(n0 & 127) * 8;
    short8 bh[2], bl[2];
    if (wave == 0) stageB64(AhP, SA, lane);
    if (wave == 1) stageB64(AlP, SA + 4 * SLABB, lane);
    loadB2(bh, bl, BhP, BlP, 0, wn0, fm, fq);
    for (int ks = 0; ks < 8; ++ks) {
      __syncthreads();
      u16* Ac = cur ? SA + 8 * SLABB : SA;
      u16* An = cur ? SA : SA + 8 * SLABB;
      if (ks < 7) {
        if (wave == 0) stageB64(AhP + (ks + 1) * 4096, An, lane);
        if (wave == 1) stageB64(AlP + (ks + 1) * 4096, An + 4 * SLABB, lane);
      }
      mfma_64_ab(Ac, Ac + 4 * SLABB, bh, bl, wm0, fm, fq, acc);
      if (ks < 7) loadB2(bh, bl, BhP, BlP, ks + 1, wn0, fm, fq);
      cur ^= 1;
    }
  }
  {  // intra: A = Sg 64-row panel (stageB64 dbuf), B = V split-bf16 -> SLABB
    const u16* AhP = Sgh + (size_t)(chunk * 2 + (m0 >> 7)) * 32768 + (size_t)(m0 & 127) * 8;
    const u16* AlP = Sgl + (size_t)(chunk * 2 + (m0 >> 7)) * 32768 + (size_t)(m0 & 127) * 8;
    const u16* BThP = VTh + ((size_t)(b * 2 + (n0 >> 7)) * 512 + c * 32) * 1024 + (size_t)(n0 & 127) * 8;
    const u16* BTlP = VTl + ((size_t)(b * 2 + (n0 >> 7)) * 512 + c * 32) * 1024 + (size_t)(n0 & 127) * 8;
    const int ber = tid >> 2, bk8 = tid & 3;  // 64 rows x 4 k8, 1 unit/thread
    const int nks = (m0 >> 5) + 2;            // causality: k <= m0+64
    short8 vh, vl;
    {  // prologue into buf[cur] (last read 2 steps ago -> safe)
      u16* Ac = cur ? SA + 8 * SLABB : SA;
      u16* Bc = cur ? SB + 8 * SLABB : SB;
      if (wave == 0) stageB64(AhP, Ac, lane);
      if (wave == 1) stageB64(AlP, Ac + 4 * SLABB, lane);
      int off = bk8 * 1024 + ber * 8;
      vh = *(const short8*)&BThP[off];
      vl = *(const short8*)&BTlP[off];
      // overlap acc scaling with the loads
#pragma unroll
      for (int i = 0; i < 2; ++i)
#pragma unroll
        for (int r = 0; r < 4; ++r) {
          int rl = wm0 + i * 16 + fq * 4 + r;
          float sc = olut[rl];
#pragma unroll
          for (int j = 0; j < 2; ++j) acc[i][j][r] *= sc;
        }
      u16 hs[8], ls[8];
#pragma unroll
      for (int u = 0; u < 8; ++u) {
        float v = (bf2f((u16)vh[u]) + bf2f((u16)vl[u])) * sdn[bk8 * 8 + u];
        u16 h = f2bf(v); hs[u] = h; ls[u] = f2bf(v - bf2f(h));
      }
      *(short8*)&Bc[bk8 * SLABB + ber * 8] = *(short8*)hs;
      *(short8*)&Bc[4 * SLABB + bk8 * SLABB + ber * 8] = *(short8*)ls;
    }
    for (int ks = 0; ks < nks; ++ks) {
      __syncthreads();
      u16* Ac = cur ? SA + 8 * SLABB : SA;
      u16* Bc = cur ? SB + 8 * SLABB : SB;
      u16* An = cur ? SA : SA + 8 * SLABB;
      u16* Bn = cur ? SB : SB + 8 * SLABB;
      if (ks + 1 < nks) {
        if (wave == 0) stageB64(AhP + (ks + 1) * 4096, An, lane);
        if (wave == 1) stageB64(AlP + (ks + 1) * 4096, An + 4 * SLABB, lane);
        int off = ((ks + 1) * 4 + bk8) * 1024 + ber * 8;
        vh = *(const short8*)&BThP[off];
        vl = *(const short8*)&BTlP[off];
      }
      mfma_64_bb(Ac, Ac + 4 * SLABB, Bc, Bc + 4 * SLABB, wm0, wn0, fm, fq, acc);
      if (ks + 1 < nks) {
        u16 hs[8], ls[8];
#pragma unroll
        for (int u = 0; u < 8; ++u) {
          float v = (bf2f((u16)vh[u]) + bf2f((u16)vl[u])) *
                    sdn[(ks + 1) * 32 + bk8 * 8 + u];
          u16 h = f2bf(v); hs[u] = h; ls[u] = f2bf(v - bf2f(h));
        }
        *(short8*)&Bn[bk8 * SLABB + ber * 8] = *(short8*)hs;
        *(short8*)&Bn[4 * SLABB + bk8 * SLABB + ber * 8] = *(short8*)ls;
      }
      cur ^= 1;
    }
  }
#pragma unroll
  for (int i = 0; i < 2; ++i)
#pragma unroll
    for (int j = 0; j < 2; ++j)
#pragma unroll
      for (int r = 0; r < 4; ++r) {
        int il = m0 + wm0 + i * 16 + fq * 4 + r;
        int e = n0 + wn0 + j * 16 + fm;
        out[(size_t)(b * SS + c * LL + il) * DD + e] = acc[i][j][r];
      }
}

// ---------------------------------------------------------------------------
extern "C" void kernel_launch(void* const* d_in, const int* in_sizes, int n_in,
                              void* d_out, int out_size, void* d_ws, size_t ws_size,
                              hipStream_t stream) {
  const float* xq = (const float*)d_in[0];
  const float* xk = (const float*)d_in[1];
  const float* xv = (const float*)d_in[2];
  const float* Wq = (const float*)d_in[3];
  const float* bq = (const float*)d_in[4];
  const float* Wk = (const float*)d_in[5];
  const float* bk = (const float*)d_in[6];
  const float* Wv = (const float*)d_in[7];
  const float* bv = (const float*)d_in[8];
  float* out = (float*)d_out;

  char* p = (char*)d_ws;
  const size_t H16 = (size_t)BB * SS * DD * 2;  // 8 MB
  u16* Qh   = (u16*)(p + 0 * H16);  u16* Ql   = (u16*)(p + 1 * H16);
  u16* Kh   = (u16*)(p + 2 * H16);  u16* Kl   = (u16*)(p + 3 * H16);
  u16* KTh  = (u16*)(p + 4 * H16);  u16* KTl  = (u16*)(p + 5 * H16);
  u16* VTh  = (u16*)(p + 6 * H16);  u16* VTl  = (u16*)(p + 7 * H16);
  u16* Sgh  = (u16*)(p + 10 * H16); u16* Sgl  = (u16*)(p + 11 * H16);
  u16* cMh  = (u16*)(p + 12 * H16); u16* cMl  = (u16*)(p + 13 * H16);
  float* lMatT = (float*)(p + 14 * H16);
  u16* Wth = (u16*)(p + 18 * H16);
  u16* Wtl = (u16*)(p + 18 * H16 + 3 * DD * DD * 2);
  float* rsP  = (float*)(p + 18 * H16 + 6 * DD * DD * 2);
  float* lVec = rsP + (size_t)BB * SS;

  init_pack_kernel<<<dim3(3, 16), 256, 0, stream>>>(Wq, Wk, Wv, Wth, Wtl, rsP, lVec);
  proj_kernel<<<dim3(BB * SS / 64, 1, 3), 256, 0, stream>>>(
      xq, xk, xv, Wth, Wtl, bq, bk, bv, Qh, Ql, Kh, Kl, KTh, KTl, VTh, VTl, lVec);
  scores_kernel<<<dim3(BB * NCH, 10), 256, 0, stream>>>(
      Qh, Ql, Kh, Kl, lVec, Sgh, Sgl, rsP);
  lmat_kernel<<<dim3(BB * NCH, 16), 256, 0, stream>>>(VTh, VTl, rsP, KTh, KTl, lMatT);
  combine_mat_kernel<<<128, 256, 0, stream>>>(lMatT, cMh, cMl);
  out_kernel<<<dim3(BB * NCH, 16), 256, 0, stream>>>(
      Qh, Ql, cMh, cMl, Sgh, Sgl, VTh, VTl, rsP, out);
}

// Round 18
// 194.417 us; speedup vs baseline: 1.0574x; 1.0056x over previous
//
#include <hip/hip_runtime.h>
#include <math.h>

// Retention (B=4, S=4096, D=256): chunkwise, split-bf16 MFMA, packed k8-slab
// operands.
// R1-R15: see history. R15/R17 = ~195us (64-row retiles; proj BM=64).
// R16: FAILED (proj BM=32). R17: reverted.
// R18: combine_mat was running 128 blocks on 256 CUs (half GPU idle, ~20us
//   for 64MB of traffic). Retiled to 1 scan/element: 262144 threads =
//   1024 blocks = 4/CU; reads stay coalesced; identical fp32 scan order.
#define BB 4
#define SS 4096
#define DD 256
#define LL 256
#define NCH 16
#define GAMMA 0.9865f
#define LOG2G (-0.019609034f)   // log2(0.9865)
#define INV1MG 74.07407407f     // 1/(1-gamma)
#define SLAB 1032               // padded LDS slab stride (u16), 128-row panels
#define SLABB 520               // padded LDS slab stride (u16), 64-row panels

typedef __attribute__((ext_vector_type(8))) short short8;
typedef __attribute__((ext_vector_type(4))) float f32x4;
typedef unsigned short u16;
typedef unsigned int u32;

__device__ __forceinline__ u16 f2bf(float f) {
  union { float f; unsigned u; } v; v.f = f;
  unsigned r = v.u + 0x7FFFu + ((v.u >> 16) & 1u);
  return (u16)(r >> 16);
}
__device__ __forceinline__ float bf2f(u16 h) {
  union { unsigned u; float f; } v; v.u = ((unsigned)h) << 16; return v.f;
}

__device__ __forceinline__ void gll16(const u16* g, u16* l) {
  __builtin_amdgcn_global_load_lds(
      (const __attribute__((address_space(1))) u32*)g,
      (__attribute__((address_space(3))) u32*)l, 16, 0, 0);
}
// stage one BK=32 k-step of 64 rows from a 128-row panel (row offset folded
// into g by caller): 4 slabs x 64 rows, SLABB stride
__device__ __forceinline__ void stageB64(const u16* g, u16* l, int lane) {
#pragma unroll
  for (int i = 0; i < 4; ++i)
    gll16(g + i * 1024 + lane * 8, l + i * SLABB);
}

// 64-row A from LDS (SLABB slabs), B regs[4]; 64x64 per wave (proj R13)
__device__ __forceinline__ void mfma_step_regB64(
    const u16* Ah, const u16* Al, const short8 bh[4], const short8 bl[4],
    int fm, int fq, f32x4 acc[4][4])
{
  const int ka = fq * SLABB;
  short8 ah[4], al[4];
#pragma unroll
  for (int i = 0; i < 4; ++i) {
    ah[i] = *(const short8*)&Ah[ka + (i * 16 + fm) * 8];
    al[i] = *(const short8*)&Al[ka + (i * 16 + fm) * 8];
  }
#pragma unroll
  for (int j = 0; j < 4; ++j)
#pragma unroll
    for (int i = 0; i < 4; ++i) {
      acc[i][j] = __builtin_amdgcn_mfma_f32_16x16x32_bf16(al[i], bh[j], acc[i][j], 0, 0, 0);
      acc[i][j] = __builtin_amdgcn_mfma_f32_16x16x32_bf16(ah[i], bl[j], acc[i][j], 0, 0, 0);
      acc[i][j] = __builtin_amdgcn_mfma_f32_16x16x32_bf16(ah[i], bh[j], acc[i][j], 0, 0, 0);
    }
}

// 64-row-A tile (SLABB stride), wave does 32x32: A rows wm0+{0,16}, B regs[2]
__device__ __forceinline__ void mfma_64_ab(
    const u16* Ah, const u16* Al, const short8 bh[2], const short8 bl[2],
    int wm0, int fm, int fq, f32x4 acc[2][2])
{
  const int ka = fq * SLABB;
  short8 ah[2], al[2];
#pragma unroll
  for (int i = 0; i < 2; ++i) {
    ah[i] = *(const short8*)&Ah[ka + (wm0 + i * 16 + fm) * 8];
    al[i] = *(const short8*)&Al[ka + (wm0 + i * 16 + fm) * 8];
  }
#pragma unroll
  for (int j = 0; j < 2; ++j)
#pragma unroll
    for (int i = 0; i < 2; ++i) {
      acc[i][j] = __builtin_amdgcn_mfma_f32_16x16x32_bf16(al[i], bh[j], acc[i][j], 0, 0, 0);
      acc[i][j] = __builtin_amdgcn_mfma_f32_16x16x32_bf16(ah[i], bl[j], acc[i][j], 0, 0, 0);
      acc[i][j] = __builtin_amdgcn_mfma_f32_16x16x32_bf16(ah[i], bh[j], acc[i][j], 0, 0, 0);
    }
}

// 64-row tile, A and B both from SLABB-stride LDS, wave 32x32 (out-intra)
__device__ __forceinline__ void mfma_64_bb(
    const u16* Ah, const u16* Al, const u16* Bh, const u16* Bl,
    int wm0, int wn0, int fm, int fq, f32x4 acc[2][2])
{
  const int ka = fq * SLABB;
  short8 ah[2], al[2];
#pragma unroll
  for (int i = 0; i < 2; ++i) {
    ah[i] = *(const short8*)&Ah[ka + (wm0 + i * 16 + fm) * 8];
    al[i] = *(const short8*)&Al[ka + (wm0 + i * 16 + fm) * 8];
  }
#pragma unroll
  for (int j = 0; j < 2; ++j) {
    short8 bh = *(const short8*)&Bh[ka + (wn0 + j * 16 + fm) * 8];
    short8 bl = *(const short8*)&Bl[ka + (wn0 + j * 16 + fm) * 8];
#pragma unroll
    for (int i = 0; i < 2; ++i) {
      acc[i][j] = __builtin_amdgcn_mfma_f32_16x16x32_bf16(al[i], bh, acc[i][j], 0, 0, 0);
      acc[i][j] = __builtin_amdgcn_mfma_f32_16x16x32_bf16(ah[i], bl, acc[i][j], 0, 0, 0);
      acc[i][j] = __builtin_amdgcn_mfma_f32_16x16x32_bf16(ah[i], bh, acc[i][j], 0, 0, 0);
    }
  }
}

// load a wave's 64-row-panel B-fragments (2 col-groups, hi+lo) from global.
__device__ __forceinline__ void loadB2(short8 bh[2], short8 bl[2],
    const u16* BhP, const u16* BlP, int ks, int wn0, int fm, int fq)
{
  const int base = ks * 4096 + fq * 1024;
#pragma unroll
  for (int j = 0; j < 2; ++j) {
    int o = base + (wn0 + j * 16 + fm) * 8;
    bh[j] = *(const short8*)&BhP[o];
    bl[j] = *(const short8*)&BlP[o];
  }
}

// ---------------------------------------------------------------------------
// 0) pack W^T slabs (hi/lo) + zero rsP/lVec accumulators. grid (3, 16).
__global__ __launch_bounds__(256) void init_pack_kernel(
    const float* __restrict__ Wq, const float* __restrict__ Wk, const float* __restrict__ Wv,
    u16* __restrict__ Wth, u16* __restrict__ Wtl,
    float* __restrict__ rsP, float* __restrict__ lVec)
{
  const int which = blockIdx.x;
  const int it = blockIdx.y;
  const int t = threadIdx.x;
  if (which == 0) {
    *(float4*)&rsP[(size_t)(it * 256 + t) * 4] = (float4){0.f, 0.f, 0.f, 0.f};
  } else if (which == 1) {
    *(float4*)&lVec[(size_t)(it * 256 + t) * 4] = (float4){0.f, 0.f, 0.f, 0.f};
  }
  const float* W = which == 0 ? Wq : (which == 1 ? Wk : Wv);
  for (int pn = 0; pn < 2; ++pn) {
    int pos = it * 256 + t;
    int k8 = pos >> 7, r = pos & 127;
    u16 hs[8], ls[8];
#pragma unroll
    for (int u = 0; u < 8; ++u) {
      float x = W[(size_t)(k8 * 8 + u) * DD + pn * 128 + r];
      u16 h = f2bf(x); hs[u] = h; ls[u] = f2bf(x - bf2f(h));
    }
    size_t o = ((size_t)((which * 2 + pn) * 32 + k8)) * 1024 + (size_t)r * 8;
    *(short8*)&Wth[o] = *(short8*)hs;
    *(short8*)&Wtl[o] = *(short8*)ls;
  }
}

// ---------------------------------------------------------------------------
// 1) projections (R13/R15 form): BM=64 x BN=256, pn merged. A: fp32 X
//    (64x32/step) reg-prefetched, split once into SLABB dbuf. B: W^T frags
//    in regs per wave (4 col-groups over its 64-col strip). 4 quarter-width
//    epilogues. 3 blocks/CU.
__global__ __launch_bounds__(256, 3) void proj_kernel(
    const float* __restrict__ xq, const float* __restrict__ xk, const float* __restrict__ xv,
    const u16* __restrict__ Wth, const u16* __restrict__ Wtl,
    const float* __restrict__ bq, const float* __restrict__ bk_, const float* __restrict__ bv,
    u16* __restrict__ Qh, u16* __restrict__ Ql,
    u16* __restrict__ Kh, u16* __restrict__ Kl,
    u16* __restrict__ KTh, u16* __restrict__ KTl,
    u16* __restrict__ VTh, u16* __restrict__ VTl,
    float* __restrict__ lVec)
{
  const int which = blockIdx.z;
  const float* bias = which == 0 ? bq : (which == 1 ? bk_ : bv);
  const int m0 = blockIdx.x * 64;
  __shared__ u16 SM[16 * SLABB];          // A dbuf (2 x (4hi+4lo) SLABB slabs)
  __shared__ float rsc[64];
  __shared__ float wlut[64];
  __shared__ float kacc[64];
  float* fb = (float*)SM;                 // 64x65 fp32 bounce (epilogue only)
  const int tid = threadIdx.x, lane = tid & 63, wave = tid >> 6;
  const int wn0g = wave * 64;             // wave's global col strip
  const int fm = lane & 15, fq = lane >> 4;
  if (which == 1 && tid < 64) {
    int sb = (m0 & (SS - 1)) + tid;
    rsc[tid] = rsqrtf((1.0f - exp2f((float)(sb + 1) * LOG2G)) * INV1MG);
    wlut[tid] = exp2f((float)(255 - ((m0 & (LL - 1)) + tid)) * LOG2G);
    kacc[tid] = 0.f;
  }
  const float* XP = (which == 0 ? xq : (which == 1 ? xk : xv)) + (size_t)m0 * DD;
  const int pnw = wn0g >> 7, wl = wn0g & 127;
  const u16* WhP = Wth + (size_t)((which * 2 + pnw) * 32) * 1024;
  const u16* WlP = Wtl + (size_t)((which * 2 + pnw) * 32) * 1024;
  const int arow = tid >> 2, ak8 = tid & 3;  // 64 rows x 4 k8, 1 unit/thread
  f32x4 acc[4][4];
#pragma unroll
  for (int i = 0; i < 4; ++i)
#pragma unroll
    for (int j = 0; j < 4; ++j) acc[i][j] = (f32x4){0.f, 0.f, 0.f, 0.f};
  float xs[8];
  short8 bh[4], bl[4];
  // prologue: W(0) into regs, X(0) into buffer 0
  {
    const int base = fq * 1024;
#pragma unroll
    for (int j = 0; j < 4; ++j) {
      int o = base + (wl + j * 16 + fm) * 8;
      bh[j] = *(const short8*)&WhP[o];
      bl[j] = *(const short8*)&WlP[o];
    }
  }
  {
    const float* src = XP + (size_t)arow * DD + ak8 * 8;
    *(float4*)&xs[0] = *(const float4*)src;
    *(float4*)&xs[4] = *(const float4*)(src + 4);
    u16 hs[8], ls[8];
#pragma unroll
    for (int u = 0; u < 8; ++u) {
      u16 h = f2bf(xs[u]); hs[u] = h; ls[u] = f2bf(xs[u] - bf2f(h));
    }
    *(short8*)&SM[ak8 * SLABB + arow * 8] = *(short8*)hs;
    *(short8*)&SM[4 * SLABB + ak8 * SLABB + arow * 8] = *(short8*)ls;
  }
  int cur = 0;
  for (int ks = 0; ks < 8; ++ks) {
    __syncthreads();                       // buf[cur] ready
    u16* Ac = SM + cur * 8 * SLABB;
    u16* An = SM + (cur ^ 1) * 8 * SLABB;
    if (ks < 7) {
      const float* src = XP + (size_t)arow * DD + (ks + 1) * 32 + ak8 * 8;
      *(float4*)&xs[0] = *(const float4*)src;
      *(float4*)&xs[4] = *(const float4*)(src + 4);
    }
    mfma_step_regB64(Ac, Ac + 4 * SLABB, bh, bl, fm, fq, acc);
    if (ks < 7) {
      const int base = (ks + 1) * 4096 + fq * 1024;
#pragma unroll
      for (int j = 0; j < 4; ++j) {        // prefetch next W frags
        int o = base + (wl + j * 16 + fm) * 8;
        bh[j] = *(const short8*)&WhP[o];
        bl[j] = *(const short8*)&WlP[o];
      }
      u16 hs[8], ls[8];
#pragma unroll
      for (int u = 0; u < 8; ++u) {
        u16 h = f2bf(xs[u]); hs[u] = h; ls[u] = f2bf(xs[u] - bf2f(h));
      }
      *(short8*)&An[ak8 * SLABB + arow * 8] = *(short8*)hs;
      *(short8*)&An[4 * SLABB + ak8 * SLABB + arow * 8] = *(short8*)ls;
    }
    cur ^= 1;
  }
  const int b = m0 >> 12, sbb = m0 & (SS - 1);
  for (int p = 0; p < 4; ++p) {            // quarter-width column passes
    __syncthreads();
    if (wn0g == p * 64) {                  // owning wave bounces acc -> fb
#pragma unroll
      for (int i = 0; i < 4; ++i)
#pragma unroll
        for (int j = 0; j < 4; ++j)
#pragma unroll
          for (int r = 0; r < 4; ++r)
            fb[(i * 16 + fq * 4 + r) * 65 + j * 16 + fm] = acc[i][j][r];
    }
    __syncthreads();
    if (which == 0) {
#pragma unroll
      for (int it = 0; it < 2; ++it) {
        int unit = it * 256 + tid;         // 8 k8 x 64 rows
        int k8l = unit >> 6, row = unit & 63;
        int gc0 = p * 64 + k8l * 8;
        u16 hs[8], ls[8];
#pragma unroll
        for (int u = 0; u < 8; ++u) {
          float v = (fb[row * 65 + k8l * 8 + u] + bias[gc0 + u]) * (1.f / 16.f);
          u16 h = f2bf(v); hs[u] = h; ls[u] = f2bf(v - bf2f(h));
        }
        size_t o = (size_t)(m0 >> 7) * 32768 + (size_t)(p * 8 + k8l) * 1024 +
                   (size_t)((m0 & 64) + row) * 8;
        *(short8*)&Qh[o] = *(short8*)hs;
        *(short8*)&Ql[o] = *(short8*)ls;
      }
    } else if (which == 1) {
#pragma unroll
      for (int it = 0; it < 2; ++it) {     // K (row-major panel)
        int unit = it * 256 + tid;
        int k8l = unit >> 6, row = unit & 63;
        int gc0 = p * 64 + k8l * 8;
        u16 hs[8], ls[8];
#pragma unroll
        for (int u = 0; u < 8; ++u) {
          float v = (fb[row * 65 + k8l * 8 + u] + bias[gc0 + u]) * rsc[row];
          u16 h = f2bf(v); hs[u] = h; ls[u] = f2bf(v - bf2f(h));
        }
        size_t o = (size_t)(m0 >> 7) * 32768 + (size_t)(p * 8 + k8l) * 1024 +
                   (size_t)((m0 & 64) + row) * 8;
        *(short8*)&Kh[o] = *(short8*)hs;
        *(short8*)&Kl[o] = *(short8*)ls;
      }
      float kpart = 0.f;
#pragma unroll
      for (int it = 0; it < 2; ++it) {     // KT (col-major packed) + lVec
        int unit = it * 256 + tid;
        int dl = unit & 63, s8l = unit >> 6;
        int gcolg = p * 64 + dl;
        float bs = bias[gcolg];
        u16 hs[8], ls[8];
#pragma unroll
        for (int u = 0; u < 8; ++u) {
          int row = s8l * 8 + u;
          float v = (fb[row * 65 + dl] + bs) * rsc[row];
          kpart = fmaf(v, wlut[row], kpart);
          u16 h = f2bf(v); hs[u] = h; ls[u] = f2bf(v - bf2f(h));
        }
        int sb0 = sbb + s8l * 8;
        size_t o = ((size_t)(b * 2 + (gcolg >> 7)) * 512 + (sb0 >> 3)) * 1024 + (size_t)(gcolg & 127) * 8;
        *(short8*)&KTh[o] = *(short8*)hs;
        *(short8*)&KTl[o] = *(short8*)ls;
      }
      atomicAdd(&kacc[tid & 63], kpart);
      __syncthreads();
      if (tid < 64) {
        int c = sbb >> 8;
        atomicAdd(&lVec[(size_t)(b * NCH + c) * DD + p * 64 + tid], kacc[tid]);
        kacc[tid] = 0.f;
      }
    } else {  // V: split-bf16, KT-packed layout
#pragma unroll
      for (int it = 0; it < 2; ++it) {
        int unit = it * 256 + tid;
        int dl = unit & 63, s8l = unit >> 6;
        int gcolg = p * 64 + dl;
        float bs = bias[gcolg];
        u16 hs[8], ls[8];
#pragma unroll
        for (int u = 0; u < 8; ++u) {
          float v = fb[(s8l * 8 + u) * 65 + dl] + bs;
          u16 h = f2bf(v); hs[u] = h; ls[u] = f2bf(v - bf2f(h));
        }
        int sb0 = sbb + s8l * 8;
        size_t o = ((size_t)(b * 2 + (gcolg >> 7)) * 512 + (sb0 >> 3)) * 1024 + (size_t)(gcolg & 127) * 8;
        *(short8*)&VTh[o] = *(short8*)hs;
        *(short8*)&VTl[o] = *(short8*)ls;
      }
    }
  }
}

// ---------------------------------------------------------------------------
// 3) Sg = mask*(Q~.K~)*g^(il-jl); fused rowsum + Q.cVec dot -> rsP atomics.
//    R14: 64x64 tiles, causal triangle grid (64 x 10). A = Q 64-row half
//    panel via stageB64 dbuf; B = K frags global->regs. Wave tile 32x32.
__global__ __launch_bounds__(256, 4) void scores_kernel(
    const u16* __restrict__ Qh, const u16* __restrict__ Ql,
    const u16* __restrict__ Kh, const u16* __restrict__ Kl,
    const float* __restrict__ lVec, u16* __restrict__ Sgh, u16* __restrict__ Sgl,
    float* __restrict__ rsP)
{
  const int chunk = blockIdx.x, b = chunk >> 4, c = chunk & 15;
  const int y = blockIdx.y;
  const int mi = (y >= 6) ? 3 : (y >= 3) ? 2 : (y >= 1) ? 1 : 0;
  const int ji = y - mi * (mi + 1) / 2;
  const int m0 = mi * 64, jn0 = ji * 64;
  __shared__ u16 SA[2 * 8 * SLABB];
  __shared__ float cv[256], lut[256], rowAcc[64], qd4[4][64];
  float* fb = (float*)SA;  // 64x65 fp32 = 16640B = |SA| (epilogue only)
  const int tid = threadIdx.x, lane = tid & 63, wave = tid >> 6;
  const int wm0 = (wave >> 1) * 32, wn0 = (wave & 1) * 32;
  const int fm = lane & 15, fq = lane >> 4;
  if (jn0 == 0) {  // inline prefix scan: cv = sum_{cp<c} gL^(c-1-cp) lVec[cp]
    const float gL = exp2f((float)LL * LOG2G);
    float s = 0.f;
    for (int cp = 0; cp < c; ++cp)
      s = fmaf(gL, s, lVec[(size_t)(b * NCH + cp) * DD + tid]);
    cv[tid] = s;
  }
  lut[tid] = exp2f((float)tid * LOG2G);
  if (tid < 64) rowAcc[tid] = 0.f;
  const int growA = b * SS + c * LL + m0;
  const int growB = b * SS + c * LL + jn0;
  const u16* QhP = Qh + (size_t)(growA >> 7) * 32768 + (size_t)(growA & 127) * 8;
  const u16* QlP = Ql + (size_t)(growA >> 7) * 32768 + (size_t)(growA & 127) * 8;
  const u16* KhP = Kh + (size_t)(growB >> 7) * 32768 + (size_t)(growB & 127) * 8;
  const u16* KlP = Kl + (size_t)(growB >> 7) * 32768 + (size_t)(growB & 127) * 8;
  f32x4 acc[2][2];
#pragma unroll
  for (int i = 0; i < 2; ++i)
#pragma unroll
    for (int j = 0; j < 2; ++j) acc[i][j] = (f32x4){0.f, 0.f, 0.f, 0.f};
  float qdreg = 0.f;
  const int qrow = tid & 63, qk8b = tid >> 6;  // 64 rows x 4 k8
  short8 bh[2], bl[2];
  if (wave == 0) stageB64(QhP, SA, lane);
  if (wave == 1) stageB64(QlP, SA + 4 * SLABB, lane);
  loadB2(bh, bl, KhP, KlP, 0, wn0, fm, fq);
  int cur = 0;
  for (int ks = 0; ks < 8; ++ks) {
    __syncthreads();
    u16* Ac = cur ? SA + 8 * SLABB : SA;
    u16* An = cur ? SA : SA + 8 * SLABB;
    if (ks < 7) {
      if (wave == 0) stageB64(QhP + (ks + 1) * 4096, An, lane);
      if (wave == 1) stageB64(QlP + (ks + 1) * 4096, An + 4 * SLABB, lane);
    }
    mfma_64_ab(Ac, Ac + 4 * SLABB, bh, bl, wm0, fm, fq, acc);
    if (ks < 7) loadB2(bh, bl, KhP, KlP, ks + 1, wn0, fm, fq);
    if (jn0 == 0) {
      short8 hv = *(const short8*)&Ac[qk8b * SLABB + qrow * 8];
      short8 lv = *(const short8*)&Ac[4 * SLABB + qk8b * SLABB + qrow * 8];
#pragma unroll
      for (int u = 0; u < 8; ++u)
        qdreg = fmaf(bf2f((u16)hv[u]) + bf2f((u16)lv[u]),
                     cv[ks * 32 + qk8b * 8 + u], qdreg);
    }
    cur ^= 1;
  }
  qd4[qk8b][qrow] = qdreg;
  const int ps = chunk * 2 + (m0 >> 7);
  __syncthreads();                          // SA reads done; fb overlay safe
#pragma unroll
  for (int i = 0; i < 2; ++i)
#pragma unroll
    for (int j = 0; j < 2; ++j)
#pragma unroll
      for (int r = 0; r < 4; ++r)
        fb[(wm0 + i * 16 + fq * 4 + r) * 65 + wn0 + j * 16 + fm] = acc[i][j][r];
  __syncthreads();
#pragma unroll
  for (int it = 0; it < 2; ++it) {
    int unit = it * 256 + tid;              // 8 k8-cols x 64 rows
    int k8l = unit >> 6, rowl = unit & 63;
    int il = m0 + rowl;
    int jlb = jn0 + k8l * 8;
    float part = 0.f;
    u16 hs[8], ls[8];
#pragma unroll
    for (int u = 0; u < 8; ++u) {
      int jl = jlb + u;
      float v = (jl <= il) ? fb[rowl * 65 + k8l * 8 + u] * lut[il - jl] : 0.f;
      part += v;
      u16 h = f2bf(v); hs[u] = h; ls[u] = f2bf(v - bf2f(h));
    }
    atomicAdd(&rowAcc[rowl], part);
    size_t o = (size_t)(ps * 32 + (jn0 >> 3) + k8l) * 1024 +
               (size_t)((m0 & 64) + rowl) * 8;
    *(short8*)&Sgh[o] = *(short8*)hs;
    *(short8*)&Sgl[o] = *(short8*)ls;
  }
  __syncthreads();
  if (tid < 64) {
    float rs = rowAcc[tid];
    if (jn0 == 0)
      rs += exp2f((float)(m0 + tid + 1) * LOG2G) *
            (qd4[0][tid] + qd4[1][tid] + qd4[2][tid] + qd4[3][tid]);
    atomicAdd(&rsP[(size_t)b * SS + c * LL + m0 + tid], rs);
  }
}

// ---------------------------------------------------------------------------
// 5) lMatT[e][d] = sum_jl Vw[jl,e] K~[jl,d] ; R14: 64x64 tiles (grid 64x16).
//    A = V split-bf16 reg-staged (hi+lo reconstruct, wtl/denom fused) ->
//    SLABB dbuf; B = KT global->regs. Wave tile 32x32.
__global__ __launch_bounds__(256, 4) void lmat_kernel(
    const u16* __restrict__ VTh, const u16* __restrict__ VTl,
    const float* __restrict__ rsP,
    const u16* __restrict__ KTh, const u16* __restrict__ KTl,
    float* __restrict__ lMatT)
{
  const int chunk = blockIdx.x, b = chunk >> 4, c = chunk & 15;
  const int ty = blockIdx.y;
  const int m0 = (ty >> 2) * 64, n0 = (ty & 3) * 64;
  __shared__ u16 SA[2 * 8 * SLABB];
  __shared__ float swl[256];
  const int tid = threadIdx.x, lane = tid & 63, wave = tid >> 6;
  const int wm0 = (wave >> 1) * 32, wn0 = (wave & 1) * 32;
  const int fm = lane & 15, fq = lane >> 4;
  // per-jl scale = gamma^(255-jl) / max(|rsP|,1)
  swl[tid] = exp2f((float)(255 - tid) * LOG2G) /
             fmaxf(fabsf(rsP[(size_t)b * SS + c * LL + tid]), 1.0f);
  const u16* AThP = VTh + ((size_t)(b * 2 + (m0 >> 7)) * 512 + c * 32) * 1024 +
                    (size_t)(m0 & 127) * 8;
  const u16* ATlP = VTl + ((size_t)(b * 2 + (m0 >> 7)) * 512 + c * 32) * 1024 +
                    (size_t)(m0 & 127) * 8;
  const u16* BhP = KTh + ((size_t)(b * 2 + (n0 >> 7)) * 512 + c * 32) * 1024 + (size_t)(n0 & 127) * 8;
  const u16* BlP = KTl + ((size_t)(b * 2 + (n0 >> 7)) * 512 + c * 32) * 1024 + (size_t)(n0 & 127) * 8;
  const int arow = tid >> 2, ak8 = tid & 3;  // 64 rows x 4 k8, 1 unit/thread
  f32x4 acc[2][2];
#pragma unroll
  for (int i = 0; i < 2; ++i)
#pragma unroll
    for (int j = 0; j < 2; ++j) acc[i][j] = (f32x4){0.f, 0.f, 0.f, 0.f};
  short8 vh, vl;
  short8 bh[2], bl[2];
  loadB2(bh, bl, BhP, BlP, 0, wn0, fm, fq);
  {
    int off = ak8 * 1024 + arow * 8;
    vh = *(const short8*)&AThP[off];
    vl = *(const short8*)&ATlP[off];
  }
  __syncthreads();                         // swl ready
  {
    u16 hs[8], ls[8];
#pragma unroll
    for (int u = 0; u < 8; ++u) {
      float v = (bf2f((u16)vh[u]) + bf2f((u16)vl[u])) * swl[ak8 * 8 + u];
      u16 h = f2bf(v); hs[u] = h; ls[u] = f2bf(v - bf2f(h));
    }
    *(short8*)&SA[ak8 * SLABB + arow * 8] = *(short8*)hs;
    *(short8*)&SA[4 * SLABB + ak8 * SLABB + arow * 8] = *(short8*)ls;
  }
  int cur = 0;
  for (int ks = 0; ks < 8; ++ks) {
    __syncthreads();
    u16* Ac = cur ? SA + 8 * SLABB : SA;
    u16* An = cur ? SA : SA + 8 * SLABB;
    if (ks < 7) {
      int off = ((ks + 1) * 4 + ak8) * 1024 + arow * 8;
      vh = *(const short8*)&AThP[off];
      vl = *(const short8*)&ATlP[off];
    }
    mfma_64_ab(Ac, Ac + 4 * SLABB, bh, bl, wm0, fm, fq, acc);
    if (ks < 7) {
      loadB2(bh, bl, BhP, BlP, ks + 1, wn0, fm, fq);
      u16 hs[8], ls[8];
#pragma unroll
      for (int u = 0; u < 8; ++u) {
        float v = (bf2f((u16)vh[u]) + bf2f((u16)vl[u])) *
                  swl[(ks + 1) * 32 + ak8 * 8 + u];
        u16 h = f2bf(v); hs[u] = h; ls[u] = f2bf(v - bf2f(h));
      }
      *(short8*)&An[ak8 * SLABB + arow * 8] = *(short8*)hs;
      *(short8*)&An[4 * SLABB + ak8 * SLABB + arow * 8] = *(short8*)ls;
    }
    cur ^= 1;
  }
#pragma unroll
  for (int i = 0; i < 2; ++i)
#pragma unroll
    for (int j = 0; j < 2; ++j)
#pragma unroll
      for (int r = 0; r < 4; ++r) {
        int e = m0 + wm0 + i * 16 + fq * 4 + r;
        int d = n0 + wn0 + j * 16 + fm;
        lMatT[(size_t)chunk * 65536 + (size_t)e * 256 + d] = acc[i][j][r];
      }
}

// 6) carry scan -> cM packed split. R18: one scan per (b,e,d) element,
//    262144 threads = 1024 blocks = 4 blocks/CU (was 128 blocks = half GPU
//    idle). Reads stay coalesced (256 threads cover 1KB contiguous d-range).
__global__ __launch_bounds__(256) void combine_mat_kernel(
    const float* __restrict__ lMatT, u16* __restrict__ cMh, u16* __restrict__ cMl)
{
  const int t = blockIdx.x * 256 + threadIdx.x;      // 262144 total
  const int b = t >> 16, rem = t & 65535;
  const int e = rem >> 8, d = rem & 255;
  const int k8 = d >> 3, u = d & 7;
  const float gL = powf(GAMMA, (float)LL);
  float s = 0.f;
  for (int ch = 0; ch < 16; ++ch) {
    size_t ro = (size_t)(b * 16 + ch) * 65536 + (size_t)e * 256 + d;
    float val = lMatT[ro];
    u16 h = f2bf(s);
    u16 l = f2bf(s - bf2f(h));
    size_t wo = ((size_t)(((b * 16 + ch) * 2 + (e >> 7)) * 32 + k8)) * 1024 +
                (size_t)(e & 127) * 8 + u;
    cMh[wo] = h;
    cMl[wo] = l;
    s = gL * s + val;
  }
}

// ---------------------------------------------------------------------------
// 7) out = g^(il+1) * Q~ @ cM^T + Sg @ Vd ; R15: 64x64 tiles (grid 64x16),
//    4 blocks/CU. inter: A=Q 64-row stageB64 dbuf, B=cM regs. intra: A=Sg
//    stageB64 dbuf, B=V split-bf16 reg-staged -> SLABB dbuf; nks=m0/32+2.
__global__ __launch_bounds__(256, 4) void out_kernel(
    const u16* __restrict__ Qh, const u16* __restrict__ Ql,
    const u16* __restrict__ cMh, const u16* __restrict__ cMl,
    const u16* __restrict__ Sgh, const u16* __restrict__ Sgl,
    const u16* __restrict__ VTh, const u16* __restrict__ VTl,
    const float* __restrict__ rsP,
    float* __restrict__ out)
{
  const int chunk = blockIdx.x, b = chunk >> 4, c = chunk & 15;
  const int ty = blockIdx.y;
  const int m0 = (ty >> 2) * 64, n0 = (ty & 3) * 64;
  __shared__ u16 SA[2 * 8 * SLABB];
  __shared__ u16 SB[2 * 8 * SLABB];
  __shared__ float olut[64];
  __shared__ float sdn[256];
  const int tid = threadIdx.x, lane = tid & 63, wave = tid >> 6;
  const int wm0 = (wave >> 1) * 32, wn0 = (wave & 1) * 32;
  const int fm = lane & 15, fq = lane >> 4;
  if (tid < 64) olut[tid] = exp2f((float)(m0 + tid + 1) * LOG2G);
  sdn[tid] = 1.0f / fmaxf(fabsf(rsP[(size_t)b * SS + c * LL + tid]), 1.0f);
  f32x4 acc[2][2];
#pragma unroll
  for (int i = 0; i < 2; ++i)
#pragma unroll
    for (int j = 0; j < 2; ++j) acc[i][j] = (f32x4){0.f, 0.f, 0.f, 0.f};
  int cur = 0;
  {  // inter: A = Q 64-row panel (stageB64 dbuf), B = cM rows n0.. (regs)
    const int growA = b * SS + c * LL + m0;
    const u16* AhP = Qh + (size_t)(growA >> 7) * 32768 + (size_t)(growA & 127) * 8;
    const u16* AlP = Ql + (size_t)(growA >> 7) * 32768 + (size_t)(growA & 127) * 8;
    const u16* BhP = cMh + (size_t)(chunk * 2 + (n0 >> 7)) * 32768 + (size_t)(n0 & 127) * 8;
    const u16* BlP = cMl + (size_t)(chunk * 2 + (n0 >> 7)) * 32768 + (size_t)(n0 & 127) * 8;
    short8 bh[2], bl[2];
    if (wave == 0) stageB64(AhP, SA, lane);
    if (wave == 1) stageB64(AlP, SA + 4 * SLABB, lane);
    loadB2(bh, bl, BhP, BlP, 0, wn0, fm, fq);
    for (int ks = 0; ks < 8; ++ks) {
      __syncthreads();
      u16* Ac = cur ? SA + 8 * SLABB : SA;
      u16* An = cur ? SA : SA + 8 * SLABB;
      if (ks < 7) {
        if (wave == 0) stageB64(AhP + (ks + 1) * 4096, An, lane);
        if (wave == 1) stageB64(AlP + (ks + 1) * 4096, An + 4 * SLABB, lane);
      }
      mfma_64_ab(Ac, Ac + 4 * SLABB, bh, bl, wm0, fm, fq, acc);
      if (ks < 7) loadB2(bh, bl, BhP, BlP, ks + 1, wn0, fm, fq);
      cur ^= 1;
    }
  }
  {  // intra: A = Sg 64-row panel (stageB64 dbuf), B = V split-bf16 -> SLABB
    const u16* AhP = Sgh + (size_t)(chunk * 2 + (m0 >> 7)) * 32768 + (size_t)(m0 & 127) * 8;
    const u16* AlP = Sgl + (size_t)(chunk * 2 + (m0 >> 7)) * 32768 + (size_t)(m0 & 127) * 8;
    const u16* BThP = VTh + ((size_t)(b * 2 + (n0 >> 7)) * 512 + c * 32) * 1024 + (size_t)(n0 & 127) * 8;
    const u16* BTlP = VTl + ((size_t)(b * 2 + (n0 >> 7)) * 512 + c * 32) * 1024 + (size_t)(n0 & 127) * 8;
    const int ber = tid >> 2, bk8 = tid & 3;  // 64 rows x 4 k8, 1 unit/thread
    const int nks = (m0 >> 5) + 2;            // causality: k <= m0+64
    short8 vh, vl;
    {  // prologue into buf[cur] (last read 2 steps ago -> safe)
      u16* Ac = cur ? SA + 8 * SLABB : SA;
      u16* Bc = cur ? SB + 8 * SLABB : SB;
      if (wave == 0) stageB64(AhP, Ac, lane);
      if (wave == 1) stageB64(AlP, Ac + 4 * SLABB, lane);
      int off = bk8 * 1024 + ber * 8;
      vh = *(const short8*)&BThP[off];
      vl = *(const short8*)&BTlP[off];
      // overlap acc scaling with the loads
#pragma unroll
      for (int i = 0; i < 2; ++i)
#pragma unroll
        for (int r = 0; r < 4; ++r) {
          int rl = wm0 + i * 16 + fq * 4 + r;
          float sc = olut[rl];
#pragma unroll
          for (int j = 0; j < 2; ++j) acc[i][j][r] *= sc;
        }
      u16 hs[8], ls[8];
#pragma unroll
      for (int u = 0; u < 8; ++u) {
        float v = (bf2f((u16)vh[u]) + bf2f((u16)vl[u])) * sdn[bk8 * 8 + u];
        u16 h = f2bf(v); hs[u] = h; ls[u] = f2bf(v - bf2f(h));
      }
      *(short8*)&Bc[bk8 * SLABB + ber * 8] = *(short8*)hs;
      *(short8*)&Bc[4 * SLABB + bk8 * SLABB + ber * 8] = *(short8*)ls;
    }
    for (int ks = 0; ks < nks; ++ks) {
      __syncthreads();
      u16* Ac = cur ? SA + 8 * SLABB : SA;
      u16* Bc = cur ? SB + 8 * SLABB : SB;
      u16* An = cur ? SA : SA + 8 * SLABB;
      u16* Bn = cur ? SB : SB + 8 * SLABB;
      if (ks + 1 < nks) {
        if (wave == 0) stageB64(AhP + (ks + 1) * 4096, An, lane);
        if (wave == 1) stageB64(AlP + (ks + 1) * 4096, An + 4 * SLABB, lane);
        int off = ((ks + 1) * 4 + bk8) * 1024 + ber * 8;
        vh = *(const short8*)&BThP[off];
        vl = *(const short8*)&BTlP[off];
      }
      mfma_64_bb(Ac, Ac + 4 * SLABB, Bc, Bc + 4 * SLABB, wm0, wn0, fm, fq, acc);
      if (ks + 1 < nks) {
        u16 hs[8], ls[8];
#pragma unroll
        for (int u = 0; u < 8; ++u) {
          float v = (bf2f((u16)vh[u]) + bf2f((u16)vl[u])) *
                    sdn[(ks + 1) * 32 + bk8 * 8 + u];
          u16 h = f2bf(v); hs[u] = h; ls[u] = f2bf(v - bf2f(h));
        }
        *(short8*)&Bn[bk8 * SLABB + ber * 8] = *(short8*)hs;
        *(short8*)&Bn[4 * SLABB + bk8 * SLABB + ber * 8] = *(short8*)ls;
      }
      cur ^= 1;
    }
  }
#pragma unroll
  for (int i = 0; i < 2; ++i)
#pragma unroll
    for (int j = 0; j < 2; ++j)
#pragma unroll
      for (int r = 0; r < 4; ++r) {
        int il = m0 + wm0 + i * 16 + fq * 4 + r;
        int e = n0 + wn0 + j * 16 + fm;
        out[(size_t)(b * SS + c * LL + il) * DD + e] = acc[i][j][r];
      }
}

// ---------------------------------------------------------------------------
extern "C" void kernel_launch(void* const* d_in, const int* in_sizes, int n_in,
                              void* d_out, int out_size, void* d_ws, size_t ws_size,
                              hipStream_t stream) {
  const float* xq = (const float*)d_in[0];
  const float* xk = (const float*)d_in[1];
  const float* xv = (const float*)d_in[2];
  const float* Wq = (const float*)d_in[3];
  const float* bq = (const float*)d_in[4];
  const float* Wk = (const float*)d_in[5];
  const float* bk = (const float*)d_in[6];
  const float* Wv = (const float*)d_in[7];
  const float* bv = (const float*)d_in[8];
  float* out = (float*)d_out;

  char* p = (char*)d_ws;
  const size_t H16 = (size_t)BB * SS * DD * 2;  // 8 MB
  u16* Qh   = (u16*)(p + 0 * H16);  u16* Ql   = (u16*)(p + 1 * H16);
  u16* Kh   = (u16*)(p + 2 * H16);  u16* Kl   = (u16*)(p + 3 * H16);
  u16* KTh  = (u16*)(p + 4 * H16);  u16* KTl  = (u16*)(p + 5 * H16);
  u16* VTh  = (u16*)(p + 6 * H16);  u16* VTl  = (u16*)(p + 7 * H16);
  u16* Sgh  = (u16*)(p + 10 * H16); u16* Sgl  = (u16*)(p + 11 * H16);
  u16* cMh  = (u16*)(p + 12 * H16); u16* cMl  = (u16*)(p + 13 * H16);
  float* lMatT = (float*)(p + 14 * H16);
  u16* Wth = (u16*)(p + 18 * H16);
  u16* Wtl = (u16*)(p + 18 * H16 + 3 * DD * DD * 2);
  float* rsP  = (float*)(p + 18 * H16 + 6 * DD * DD * 2);
  float* lVec = rsP + (size_t)BB * SS;

  init_pack_kernel<<<dim3(3, 16), 256, 0, stream>>>(Wq, Wk, Wv, Wth, Wtl, rsP, lVec);
  proj_kernel<<<dim3(BB * SS / 64, 1, 3), 256, 0, stream>>>(
      xq, xk, xv, Wth, Wtl, bq, bk, bv, Qh, Ql, Kh, Kl, KTh, KTl, VTh, VTl, lVec);
  scores_kernel<<<dim3(BB * NCH, 10), 256, 0, stream>>>(
      Qh, Ql, Kh, Kl, lVec, Sgh, Sgl, rsP);
  lmat_kernel<<<dim3(BB * NCH, 16), 256, 0, stream>>>(VTh, VTl, rsP, KTh, KTl, lMatT);
  combine_mat_kernel<<<1024, 256, 0, stream>>>(lMatT, cMh, cMl);
  out_kernel<<<dim3(BB * NCH, 16), 256, 0, stream>>>(
      Qh, Ql, cMh, cMl, Sgh, Sgl, VTh, VTl, rsP, out);
}